// Round 5
// baseline (843.928 us; speedup 1.0000x reference)
//
#include <hip/hip_runtime.h>
#include <math.h>

// ---------------- constants ----------------
#define INV_EPS_L2E 577.0780163555854f   // (1/eps) * log2(e) = 1/(eps*ln2)
#define EPS_LOGN 0.02079441542f          // eps * ln(4096) = -eps*loga
#define EPS_LN2 0.00173286795f           // eps * ln(2)

#define NPTS 4096
#define CHUNK 64
#define NCH 64            // 4096/64
#define CPT 4             // columns per thread (2 packed pairs)
#define COLS_PER_BLK 1024 // 256*CPT
#define NCB 4             // 4096/1024
#define QSTRIDE (NCH * NPTS)  // float2 elements per problem in partial arrays

typedef float v2f __attribute__((ext_vector_type(2)));

// True packed-fp32 ops with VOP3P op_sel broadcasts. gfx950 packed-f32 set is
// ONLY {v_pk_fma_f32, v_pk_mul_f32, v_pk_add_f32} — no v_pk_max_f32.
__device__ __forceinline__ v2f pk_add(v2f a, v2f b) {
    v2f d;
    asm("v_pk_add_f32 %0, %1, %2" : "=v"(d) : "v"(a), "v"(b));
    return d;
}
// lo(a) broadcast to both lanes; b,c normal
__device__ __forceinline__ v2f pk_fma_blo(v2f a, v2f b, v2f c) {
    v2f d;
    asm("v_pk_fma_f32 %0, %1, %2, %3 op_sel:[0,0,0] op_sel_hi:[0,1,1]"
        : "=v"(d) : "v"(a), "v"(b), "v"(c));
    return d;
}
// hi(a) broadcast; b,c normal
__device__ __forceinline__ v2f pk_fma_bhi(v2f a, v2f b, v2f c) {
    v2f d;
    asm("v_pk_fma_f32 %0, %1, %2, %3 op_sel:[1,0,0] op_sel_hi:[1,1,1]"
        : "=v"(d) : "v"(a), "v"(b), "v"(c));
    return d;
}
// lo(a) broadcast AND hi(c) broadcast; b normal   (a.lo*b + c.hi per lane)
__device__ __forceinline__ v2f pk_fma_blo_chi(v2f a, v2f b, v2f c) {
    v2f d;
    asm("v_pk_fma_f32 %0, %1, %2, %3 op_sel:[0,0,1] op_sel_hi:[0,1,1]"
        : "=v"(d) : "v"(a), "v"(b), "v"(c));
    return d;
}
// a + hi(b) broadcast
__device__ __forceinline__ v2f pk_add_bhi(v2f a, v2f b) {
    v2f d;
    asm("v_pk_add_f32 %0, %1, %2 op_sel:[0,1] op_sel_hi:[1,1]"
        : "=v"(d) : "v"(a), "v"(b));
    return d;
}

// accumulator slots (floats) at start of workspace
constexpr int A_SSIMA  = 0;   // [B]
constexpr int A_SSIMB  = 2;   // [B]
constexpr int A_SSIMC  = 4;   // [B]
constexpr int A_CH1    = 6;
constexpr int A_CH2    = 7;
constexpr int A_AUX    = 8;
constexpr int A_INT    = 9;
constexpr int A_LOUT   = 10;  // [B]
constexpr int A_CNT    = 12;  // [B]
constexpr int A_SMOOTH = 14;
constexpr int A_SINK   = 16;  // [6]
constexpr int A_MAX    = 32;  // 8 uint slots (4 fields x B), float-bits
constexpr int A_DONE   = 40;  // uint: last-block-done counter for val+finalize

// ---------------- block reduction helpers (blockDim == 256) ----------------
__device__ __forceinline__ float blockSum(float v, int tid) {
#pragma unroll
    for (int o = 32; o; o >>= 1) v += __shfl_down(v, o, 64);
    __shared__ float sh[4];
    __syncthreads();
    if ((tid & 63) == 0) sh[tid >> 6] = v;
    __syncthreads();
    return sh[0] + sh[1] + sh[2] + sh[3];
}

__device__ __forceinline__ float blockMax(float v, int tid) {
#pragma unroll
    for (int o = 32; o; o >>= 1) v = fmaxf(v, __shfl_down(v, o, 64));
    __shared__ float sh[4];
    __syncthreads();
    if ((tid & 63) == 0) sh[tid >> 6] = v;
    __syncthreads();
    return fmaxf(fmaxf(sh[0], sh[1]), fmaxf(sh[2], sh[3]));
}

// -------- fused prep (y_gray, intensity, L_out, cnt) + avgpool2 + gather ----
// grid (336, 2): x<256 prep, x<320 pool, else gather (16 blocks per y-slice)
__global__ __launch_bounds__(256) void egf_prep_pool(const float* __restrict__ y,
                                                     const float* __restrict__ pet,
                                                     const float* __restrict__ mri,
                                                     const float* __restrict__ mask,
                                                     const int* __restrict__ idx,
                                                     float* __restrict__ ygray,
                                                     float* __restrict__ py,
                                                     float* __restrict__ pmri,
                                                     float4* __restrict__ pts,
                                                     float* __restrict__ acc) {
    int b = blockIdx.y;
    if (blockIdx.x < 256) {
        int p = blockIdx.x * 256 + threadIdx.x;      // exactly 65536
        float m  = mask[b * 65536 + p];
        float y0 = y[(b * 3 + 0) * 65536 + p];
        float y1 = y[(b * 3 + 1) * 65536 + p];
        float y2 = y[(b * 3 + 2) * 65536 + p];
        float q0 = pet[(b * 3 + 0) * 65536 + p];
        float q1 = pet[(b * 3 + 1) * 65536 + p];
        float q2 = pet[(b * 3 + 2) * 65536 + p];
        ygray[b * 65536 + p] = (y0 + y1 + y2) * (1.0f / 3.0f);
        float d0 = m * y0 - m * q0, d1 = m * y1 - m * q1, d2 = m * y2 - m * q2;
        float inten = d0 * d0 + d1 * d1 + d2 * d2;
        float im = 1.0f - m;
        float o0 = y0 * im, o1 = y1 * im, o2 = y2 * im;
        float lout = o0 * o0 + o1 * o1 + o2 * o2;
        float cnt = (m > 0.1f) ? 1.0f : 0.0f;
        float t;
        t = blockSum(inten, threadIdx.x); if (threadIdx.x == 0) atomicAdd(&acc[A_INT], t);
        t = blockSum(lout,  threadIdx.x); if (threadIdx.x == 0) atomicAdd(&acc[A_LOUT + b], t);
        t = blockSum(cnt,   threadIdx.x); if (threadIdx.x == 0) atomicAdd(&acc[A_CNT + b], t);
    } else if (blockIdx.x < 320) {
        int po = (blockIdx.x - 256) * 256 + threadIdx.x;  // exactly 16384
        int i = po >> 7, j = po & 127;
        int p0 = (i * 2) * 256 + j * 2;
        float s = 0.0f;
#pragma unroll
        for (int c = 0; c < 3; c++) {
            const float* ip = y + (b * 3 + c) * 65536;
            s += ip[p0] + ip[p0 + 1] + ip[p0 + 256] + ip[p0 + 257];
        }
        py[b * 16384 + po] = s * (1.0f / 12.0f);
        const float* mp = mri + b * 65536;
        pmri[b * 16384 + po] = (mp[p0] + mp[p0 + 1] + mp[p0 + 256] + mp[p0 + 257]) * 0.25f;
    } else {
        // gather masked point clouds (independent of everything above)
        int t = (b * 16 + (blockIdx.x - 320)) * 256 + threadIdx.x;   // < 8192
        int bb = t >> 12, j = t & 4095;
        int p = idx[bb * 4096 + j];
        float m = mask[bb * 65536 + p];
        float a0 = y[(bb * 3 + 0) * 65536 + p] * m;
        float a1 = y[(bb * 3 + 1) * 65536 + p] * m;
        float a2 = y[(bb * 3 + 2) * 65536 + p] * m;
        pts[(bb * 2 + 0) * 4096 + j] = make_float4(a0, a1, a2, 0.5f * (a0 * a0 + a1 * a1 + a2 * a2));
        float c0 = pet[(bb * 3 + 0) * 65536 + p] * m;
        float c1 = pet[(bb * 3 + 1) * 65536 + p] * m;
        float c2 = pet[(bb * 3 + 2) * 65536 + p] * m;
        pts[(bb * 2 + 1) * 4096 + j] = make_float4(c0, c1, c2, 0.5f * (c0 * c0 + c1 * c1 + c2 * c2));
    }
}

// ---------------- 4 sobel passes fused (grid.x partitions the 4 images) -----
__global__ __launch_bounds__(256) void egf_sobel4(const float* __restrict__ yg,
                                                  const float* __restrict__ mri,
                                                  const float* __restrict__ py,
                                                  const float* __restrict__ pmri,
                                                  float* __restrict__ mag_yg,
                                                  float* __restrict__ mag_mri,
                                                  float* __restrict__ mag_py,
                                                  float* __restrict__ mag_pmri,
                                                  unsigned* __restrict__ mx) {
    int b = blockIdx.y;
    int x = blockIdx.x;
    const float* in; float* mag; int H, logH, slot, p;
    if (x < 256)      { in = yg;   mag = mag_yg;   H = 256; logH = 8; slot = 0; p = x * 256 + threadIdx.x; }
    else if (x < 512) { in = mri;  mag = mag_mri;  H = 256; logH = 8; slot = 2; p = (x - 256) * 256 + threadIdx.x; }
    else if (x < 576) { in = py;   mag = mag_py;   H = 128; logH = 7; slot = 4; p = (x - 512) * 256 + threadIdx.x; }
    else              { in = pmri; mag = mag_pmri; H = 128; logH = 7; slot = 6; p = (x - 576) * 256 + threadIdx.x; }
    int HH = H * H;
    const float* ip = in + b * HH;
    int i = p >> logH, j = p & (H - 1);
    auto at = [&](int ii, int jj) -> float {
        return (ii >= 0 && ii < H && jj >= 0 && jj < H) ? ip[(ii << logH) + jj] : 0.0f;
    };
    float a00 = at(i - 1, j - 1), a01 = at(i - 1, j), a02 = at(i - 1, j + 1);
    float a10 = at(i, j - 1),                         a12 = at(i, j + 1);
    float a20 = at(i + 1, j - 1), a21 = at(i + 1, j), a22 = at(i + 1, j + 1);
    float gx = a00 - a02 + 2.0f * a10 - 2.0f * a12 + a20 - a22;
    float gy = a00 + 2.0f * a01 + a02 - a20 - 2.0f * a21 - a22;
    float m = sqrtf(gx * gx + gy * gy + 1e-6f);
    mag[b * HH + p] = m;
    float bm = blockMax(m, threadIdx.x);
    if (threadIdx.x == 0) atomicMax(mx + slot + b, __float_as_uint(bm));
}

// ---------------- 2 charbonnier passes fused ----------------
__global__ __launch_bounds__(256) void egf_charb2(const float* __restrict__ mag_yg,
                                                  const float* __restrict__ mag_mri,
                                                  const float* __restrict__ mag_py,
                                                  const float* __restrict__ mag_pmri,
                                                  const unsigned* __restrict__ mx,
                                                  const float* __restrict__ ehat,
                                                  float* __restrict__ acc) {
    int b = blockIdx.y;
    int x = blockIdx.x;
    const float *magA, *magB; const unsigned *mxA, *mxB;
    float *accC; const float* eh; int HH, p;
    if (x < 256) { magA = mag_yg; magB = mag_mri; mxA = mx + 0; mxB = mx + 2;
                   accC = acc + A_CH1; eh = ehat; HH = 65536; p = x * 256 + threadIdx.x; }
    else         { magA = mag_py; magB = mag_pmri; mxA = mx + 4; mxB = mx + 6;
                   accC = acc + A_CH2; eh = nullptr; HH = 16384; p = (x - 256) * 256 + threadIdx.x; }
    float c = 0.0f, au = 0.0f;
    float da = fmaxf(__uint_as_float(mxA[b]), 1e-6f);
    float db = fmaxf(__uint_as_float(mxB[b]), 1e-6f);
    if (p < HH) {
        float sa = magA[b * HH + p] / da;
        float sb = magB[b * HH + p] / db;
        float d = sa - sb;
        c = sqrtf(d * d + 1e-6f);
        if (eh) au = fabsf(eh[b * HH + p] - sb);
    }
    float tc = blockSum(c, threadIdx.x);
    if (threadIdx.x == 0) atomicAdd(accC, tc);
    if (eh) {
        float ta = blockSum(au, threadIdx.x);
        if (threadIdx.x == 0) atomicAdd(&acc[A_AUX], ta);
    }
}

// ------- SSIM, SEPARABLE: vertical 11-tap -> 5 LDS planes -> horizontal -----
// 3 configs fused via z (z<2: yg/mri, <8: y/pet, else masked y/mri)
__global__ __launch_bounds__(256) void egf_ssim3(const float* __restrict__ y,
                                                 const float* __restrict__ ygray,
                                                 const float* __restrict__ mri,
                                                 const float* __restrict__ pet,
                                                 const float* __restrict__ mask,
                                                 float* __restrict__ acc) {
    int z = blockIdx.z;
    const float *xp, *yp, *mp = nullptr; float* accB; int b;
    if (z < 2) {
        b = z; xp = ygray + b * 65536; yp = mri + b * 65536; accB = acc + A_SSIMA;
    } else if (z < 8) {
        int bc = z - 2; b = bc / 3; int c = bc - b * 3;
        xp = y + (b * 3 + c) * 65536; yp = pet + (b * 3 + c) * 65536; accB = acc + A_SSIMB;
    } else {
        int bc = z - 8; b = bc / 3; int c = bc - b * 3;
        xp = y + (b * 3 + c) * 65536; yp = mri + b * 65536; mp = mask + b * 65536; accB = acc + A_SSIMC;
    }
    __shared__ float sx[26][27];
    __shared__ float sy[26][27];
    __shared__ float va[16][27];   // vert-filtered x
    __shared__ float vb[16][27];   // vert-filtered y
    __shared__ float vc[16][27];   // vert-filtered x*x
    __shared__ float vd[16][27];   // vert-filtered y*y
    __shared__ float ve[16][27];   // vert-filtered x*y
    int ti = blockIdx.x * 16, tj = blockIdx.y * 16;
    int tid = threadIdx.y * 16 + threadIdx.x;
    for (int t = tid; t < 26 * 26; t += 256) {
        int li = t / 26, lj = t - li * 26;
        int gi = ti + li, gj = tj + lj;
        float a = 0.0f, bb = 0.0f;
        if (gi < 256 && gj < 256) {
            int p = (gi << 8) + gj;
            float m = mp ? mp[p] : 1.0f;
            a = xp[p] * m; bb = yp[p] * m;
        }
        sx[li][lj] = a; sy[li][lj] = bb;
    }
    float w[11];
    {
        float s = 0.0f;
#pragma unroll
        for (int i = 0; i < 11; i++) { float d = (float)(i - 5); w[i] = expf(-d * d * (1.0f / 4.5f)); s += w[i]; }
        float inv = 1.0f / s;
#pragma unroll
        for (int i = 0; i < 11; i++) w[i] *= inv;
    }
    __syncthreads();
    // vertical pass: 16 output rows x 26 cols
    for (int t = tid; t < 16 * 26; t += 256) {
        int r = t / 26, c = t - r * 26;
        float s0 = 0, s1 = 0, s2 = 0, s3 = 0, s4 = 0;
#pragma unroll
        for (int k = 0; k < 11; k++) {
            float wk = w[k];
            float a = sx[r + k][c], bb = sy[r + k][c];
            s0 += wk * a; s1 += wk * bb;
            s2 += wk * a * a; s3 += wk * bb * bb; s4 += wk * a * bb;
        }
        va[r][c] = s0; vb[r][c] = s1; vc[r][c] = s2; vd[r][c] = s3; ve[r][c] = s4;
    }
    __syncthreads();
    // horizontal pass: one output per thread
    int oi = ti + threadIdx.y, oj = tj + threadIdx.x;
    float val = 0.0f;
    if (oi < 246 && oj < 246) {
        float mu1 = 0, mu2 = 0, xx = 0, yy = 0, xy = 0;
        int ty = threadIdx.y, tx = threadIdx.x;
#pragma unroll
        for (int k = 0; k < 11; k++) {
            float wk = w[k];
            mu1 += wk * va[ty][tx + k]; mu2 += wk * vb[ty][tx + k];
            xx  += wk * vc[ty][tx + k]; yy  += wk * vd[ty][tx + k];
            xy  += wk * ve[ty][tx + k];
        }
        float s11 = xx - mu1 * mu1, s22 = yy - mu2 * mu2, s12 = xy - mu1 * mu2;
        const float C1 = 1e-4f, C2 = 9e-4f;
        val = ((2.0f * mu1 * mu2 + C1) * (2.0f * s12 + C2)) /
              ((mu1 * mu1 + mu2 * mu2 + C1) * (s11 + s22 + C2));
    }
    float tot = blockSum(val, tid);
    if (tid == 0) atomicAdd(&accB[b], tot);
}

// ---------------- gaussian smooth, one-pass LDS-tiled ----------------
__device__ __forceinline__ int refl256(int i) { return i < 0 ? -1 - i : (i > 255 ? 511 - i : i); }

__device__ __forceinline__ void gauss9(float* w) {
    float s = 0.0f;
#pragma unroll
    for (int t = 0; t < 9; t++) { float d = (float)(t - 4); w[t] = expf(-0.5f * d * d); s += w[t]; }
    float inv = 1.0f / s;
#pragma unroll
    for (int t = 0; t < 9; t++) w[t] *= inv;
}

__global__ __launch_bounds__(256) void egf_smooth1(const float* __restrict__ y,
                                                   float* __restrict__ acc) {
    int bc = blockIdx.z;
    int i0 = blockIdx.x * 16, j0 = blockIdx.y * 16;
    const float* ip = y + bc * 65536;
    __shared__ float sx[24][25];
    __shared__ float sv[16][25];
    int tid = threadIdx.x;
    float w[9]; gauss9(w);
    for (int t = tid; t < 576; t += 256) {
        int li = t / 24, lj = t - li * 24;
        int gi = refl256(i0 + li - 4), gj = refl256(j0 + lj - 4);
        sx[li][lj] = ip[(gi << 8) + gj];
    }
    __syncthreads();
    for (int t = tid; t < 384; t += 256) {
        int li = t / 24, lj = t - li * 24;     // li in [0,16), lj in [0,24)
        float s = 0.0f;
#pragma unroll
        for (int k = 0; k < 9; k++) s += w[k] * sx[li + k][lj];
        sv[li][lj] = s;
    }
    __syncthreads();
    int ty = tid >> 4, tx = tid & 15;
    float s = 0.0f;
#pragma unroll
    for (int k = 0; k < 9; k++) s += w[k] * sv[ty][tx + k];
    float d = s - sx[ty + 4][tx + 4];
    float tt = blockSum(d * d, tid);
    if (tid == 0) atomicAdd(acc, tt);
}

// ---------------- fused combine (staging) helper, NCH=64, float2 partials ----
__device__ __forceinline__ float stageCombine(const float2* __restrict__ Pin,
                                              int qbase, int row, int h, int r_local,
                                              float* sm, float* ss, int tid) {
    const float2* p = Pin + qbase + (h * 16) * NPTS + row;
    float2 t[16];
#pragma unroll
    for (int k = 0; k < 16; k++) t[k] = p[k * NPTS];
    float m16 = -3.4e38f;
#pragma unroll
    for (int k = 0; k < 16; k++) m16 = fmaxf(m16, t[k].x);
    float s16 = 0.0f;
#pragma unroll
    for (int k = 0; k < 16; k++) s16 += t[k].y * __builtin_amdgcn_exp2f(t[k].x - m16);
    sm[h * 64 + r_local] = m16;
    ss[h * 64 + r_local] = s16;
    __syncthreads();
    float v = 0.0f;
    if (tid < 64) {
        float m0 = sm[tid], m1 = sm[64 + tid], m2 = sm[128 + tid], m3 = sm[192 + tid];
        float M = fmaxf(fmaxf(m0, m1), fmaxf(m2, m3));
        float S = ss[tid]       * __builtin_amdgcn_exp2f(m0 - M) +
                  ss[64 + tid]  * __builtin_amdgcn_exp2f(m1 - M) +
                  ss[128 + tid] * __builtin_amdgcn_exp2f(m2 - M) +
                  ss[192 + tid] * __builtin_amdgcn_exp2f(m3 - M);
        v = EPS_LOGN - EPS_LN2 * (M + log2f(S));
    }
    return v;
}

// ---------------- sinkhorn half: packed fp32 + op_sel broadcast, CHUNK=64 ----
// CPT=4 / NCB=4: 1536 blocks = 6 blocks/CU = 24 waves/CU (vs 3/12 at CPT=8).
// Default launch bounds (no min-waves) so no VGPR cap / no spill risk.
__global__ __launch_bounds__(256) void egf_sink_half8(const float4* __restrict__ pts,
                                                      const float2* __restrict__ Pin,
                                                      float2* __restrict__ Pout,
                                                      int dir, int init) {
    int q = blockIdx.z; int b = q / 3, t = q - b * 3;
    int xsel = (t == 2) ? 1 : 0;
    int ysel = (t == 1) ? 0 : 1;
    const float4* rowP = pts + (b * 2 + (dir ? ysel : xsel)) * NPTS;
    const float4* colP = pts + (b * 2 + (dir ? xsel : ysel)) * NPTS;

    __shared__ float4 srow[CHUNK];
    __shared__ float sm[256], ss[256];
    int tid = threadIdx.x;
    int chunk = blockIdx.y;
    int r_local = tid & 63, h = tid >> 6;
    int row = chunk * CHUNK + r_local;

    // prefetch column fragments (independent of the staging barrier)
    int col0 = blockIdx.x * COLS_PER_BLK + tid;
    float4 cf[4];
#pragma unroll
    for (int k = 0; k < 4; k++) cf[k] = colP[col0 + k * 256];

    float v = 0.0f;
    if (!init)
        v = stageCombine(Pin, q * QSTRIDE, row, h, r_local, sm, ss, tid);
    if (tid < 64) {
        float4 pp = rowP[row];
        srow[tid] = make_float4(pp.x * INV_EPS_L2E, pp.y * INV_EPS_L2E,
                                pp.z * INV_EPS_L2E, (v - pp.w) * INV_EPS_L2E);
    }
    __syncthreads();

    v2f cx[2], cy[2], cz[2], cw[2];
#pragma unroll
    for (int p = 0; p < 2; p++) {
        cx[p] = (v2f){cf[2 * p].x, cf[2 * p + 1].x};
        cy[p] = (v2f){cf[2 * p].y, cf[2 * p + 1].y};
        cz[p] = (v2f){cf[2 * p].z, cf[2 * p + 1].z};
        cw[p] = (v2f){cf[2 * p].w * INV_EPS_L2E, cf[2 * p + 1].w * INV_EPS_L2E};
    }
    v2f mx[2];
#pragma unroll
    for (int p = 0; p < 2; p++) mx[p] = (v2f){-3.4e38f, -3.4e38f};
#pragma unroll 4
    for (int rr = 0; rr < CHUNK; rr++) {
        float4 rp = srow[rr];
        v2f rxy = (v2f){rp.x, rp.y};
        v2f rzw = (v2f){rp.z, rp.w};
#pragma unroll
        for (int p = 0; p < 2; p++) {
            v2f e = pk_fma_blo_chi(rzw, cz[p], rzw);   // Z*cz + W
            e = pk_fma_bhi(rxy, cy[p], e);             // + Y*cy
            e = pk_fma_blo(rxy, cx[p], e);             // + X*cx
            mx[p].x = fmaxf(mx[p].x, e.x);
            mx[p].y = fmaxf(mx[p].y, e.y);
        }
    }
    v2f mneg[2], sa[2];
#pragma unroll
    for (int p = 0; p < 2; p++) { mneg[p] = -mx[p]; sa[p] = (v2f){0.0f, 0.0f}; }
#pragma unroll 4
    for (int rr = 0; rr < CHUNK; rr++) {
        float4 rp = srow[rr];
        v2f rxy = (v2f){rp.x, rp.y};
        v2f rzw = (v2f){rp.z, rp.w};
#pragma unroll
        for (int p = 0; p < 2; p++) {
            v2f e = pk_fma_blo(rzw, cz[p], mneg[p]);   // Z*cz - mx
            e = pk_fma_bhi(rxy, cy[p], e);             // + Y*cy
            e = pk_fma_blo(rxy, cx[p], e);             // + X*cx
            e = pk_add_bhi(e, rzw);                    // + W
            v2f ex;
            ex.x = __builtin_amdgcn_exp2f(e.x);
            ex.y = __builtin_amdgcn_exp2f(e.y);
            sa[p] = pk_add(sa[p], ex);
        }
    }
    float2* om = Pout + q * QSTRIDE + chunk * NPTS;
#pragma unroll
    for (int p = 0; p < 2; p++) {
        om[col0 + (2 * p) * 256]     = make_float2(mx[p].x - cw[p].x, sa[p].x);
        om[col0 + (2 * p + 1) * 256] = make_float2(mx[p].y - cw[p].y, sa[p].y);
    }
}

// ---------------- final scalar assembly (device helper) ----------------
__device__ __forceinline__ void finalize_body(float* acc, float* out) {
    auto rd = [&](int i) -> float { return atomicAdd(&acc[i], 0.0f); };
    const float AREA = 246.0f * 246.0f;
    float ssim_m = 1.0f - (rd(A_SSIMA) + rd(A_SSIMA + 1)) / (2.0f * AREA);
    float ssim_p = 1.0f - (rd(A_SSIMB) + rd(A_SSIMB + 1)) / (2.0f * 3.0f * AREA);
    float g_cons = rd(A_CH1) / (2.0f * 65536.0f) + rd(A_CH2) / (2.0f * 16384.0f);
    float aux = rd(A_AUX) / (2.0f * 65536.0f);
    float inc0 = (rd(A_CNT)     >= 31.5f) ? 1.0f : 0.0f;
    float inc1 = (rd(A_CNT + 1) >= 31.5f) ? 1.0f : 0.0f;
    float v0 = rd(A_SINK + 0), v1 = rd(A_SINK + 1), v2 = rd(A_SINK + 2);
    float v3 = rd(A_SINK + 3), v4 = rd(A_SINK + 4), v5 = rd(A_SINK + 5);
    float Lt = (inc0 * (v0 - 0.5f * v1 - 0.5f * v2) +
                inc1 * (v3 - 0.5f * v4 - 0.5f * v5)) * 0.5f;
    float Lo = (inc0 * rd(A_LOUT) + inc1 * rd(A_LOUT + 1)) / (3.0f * 65536.0f) * 0.5f;
    float Ls = (inc0 * (1.0f - rd(A_SSIMC) / (3.0f * AREA)) +
                inc1 * (1.0f - rd(A_SSIMC + 1) / (3.0f * AREA))) * 0.5f;
    float Li = 2.5f * rd(A_INT) / (2.0f * 3.0f * 65536.0f);
    float Lsm = rd(A_SMOOTH) / (2.0f * 3.0f * 65536.0f);
    float total = 0.8f * Lt + 0.3f * Lo + 0.5f * Ls + Li + 0.2f * Lsm;
    out[0] = total; out[1] = ssim_m; out[2] = ssim_p; out[3] = g_cons; out[4] = aux;
}

// ---------------- sinkhorn value + last-block finalize ----------------
// grid (128, 6): blockIdx.x>>6 selects f/g partials, &63 selects the 64-row chunk.
__global__ __launch_bounds__(256) void egf_sink_val8(const float2* __restrict__ Pf,
                                                     const float2* __restrict__ Pg,
                                                     float* __restrict__ acc,
                                                     float* __restrict__ out) {
    int q = blockIdx.y;
    int side = blockIdx.x >> 6;
    int chunk = blockIdx.x & 63;
    const float2* P = side ? Pg : Pf;
    __shared__ float sm[256], ss[256];
    int tid = threadIdx.x;
    int r_local = tid & 63, h = tid >> 6;
    int row = chunk * CHUNK + r_local;
    float v = stageCombine(P, q * QSTRIDE, row, h, r_local, sm, ss, tid);
    float tot = blockSum(v, tid);
    if (tid == 0) {
        atomicAdd(&acc[A_SINK + q], tot * (1.0f / 4096.0f));
        __threadfence();
        unsigned old = atomicAdd((unsigned*)&acc[A_DONE], 1u);
        if (old == 128u * 6u - 1u) finalize_body(acc, out);   // last block finalizes
    }
}

// ---------------- host launch ----------------
extern "C" void kernel_launch(void* const* d_in, const int* in_sizes, int n_in,
                              void* d_out, int out_size, void* d_ws, size_t ws_size,
                              hipStream_t stream) {
    const float* y    = (const float*)d_in[0];
    const float* mri  = (const float*)d_in[1];
    const float* pet  = (const float*)d_in[2];
    const float* mask = (const float*)d_in[3];
    const float* ehat = (const float*)d_in[4];
    const int*   idx  = (const int*)d_in[5];
    float* out = (float*)d_out;
    float* ws  = (float*)d_ws;

    float* acc   = ws;                    // 64 floats
    float4* pts  = (float4*)(ws + 64);    // 4*4096 float4 = 65536 floats
    float* base  = ws + 64 + 65536;

    // sinkhorn partials: 2 float2-planes of 6*64*4096 elements (12.6 MB apiece)
    float2* Pf = (float2*)base;
    float2* Pg = Pf + QSTRIDE * 6;
    float* ibase = base + 4 * QSTRIDE * 6;

    // image scratch
    float* ygray    = ibase;              // 131072
    float* py       = ygray + 131072;     // 32768
    float* pmri     = py + 32768;         // 32768
    float* mag_yg   = pmri + 32768;       // 131072
    float* mag_mri  = mag_yg + 131072;    // 131072
    float* mag_py   = mag_mri + 131072;   // 32768
    float* mag_pmri = mag_py + 32768;     // 32768

    hipMemsetAsync(acc, 0, 64 * sizeof(float), stream);

    unsigned* mx = (unsigned*)(acc + A_MAX);

    egf_prep_pool<<<dim3(336, 2), 256, 0, stream>>>(y, pet, mri, mask, idx,
                                                    ygray, py, pmri, pts, acc);
    egf_sobel4<<<dim3(640, 2), 256, 0, stream>>>(ygray, mri, py, pmri,
                                                 mag_yg, mag_mri, mag_py, mag_pmri, mx);
    egf_charb2<<<dim3(320, 2), 256, 0, stream>>>(mag_yg, mag_mri, mag_py, mag_pmri, mx, ehat, acc);
    egf_ssim3<<<dim3(16, 16, 14), dim3(16, 16), 0, stream>>>(y, ygray, mri, pet, mask, acc);
    egf_smooth1<<<dim3(16, 16, 6), 256, 0, stream>>>(y, acc + A_SMOOTH);

    dim3 sgrid(NCB, NCH, 6);   // 4 x 64 x 6 = 1536 blocks
    for (int it = 0; it < 11; ++it) {
        egf_sink_half8<<<sgrid, 256, 0, stream>>>(pts, Pf, Pg, 0, it == 0 ? 1 : 0);
        egf_sink_half8<<<sgrid, 256, 0, stream>>>(pts, Pg, Pf, 1, 0);
    }
    egf_sink_val8<<<dim3(128, 6), 256, 0, stream>>>(Pf, Pg, acc, out);
}

// Round 8
// 784.616 us; speedup vs baseline: 1.0756x; 1.0756x over previous
//
#include <hip/hip_runtime.h>
#include <math.h>

// ---------------- constants ----------------
#define INV_EPS_L2E 577.0780163555854f   // (1/eps) * log2(e) = 1/(eps*ln2)
#define EPS_LOGN 0.02079441542f          // eps * ln(4096) = -eps*loga
#define EPS_LN2 0.00173286795f           // eps * ln(2)

#define NPTS 4096
#define CHUNK 64
#define NCH 64            // 4096/64
#define CPT 8             // columns per thread (4 packed pairs)
#define COLS_PER_BLK 2048 // 256*CPT
#define NCB 2             // 4096/2048
#define QSTRIDE (NCH * NPTS)  // float elements per problem in partial arrays (lse format)

typedef float v2f __attribute__((ext_vector_type(2)));

// True packed-fp32 ops with VOP3P op_sel broadcasts. gfx950 packed-f32 set is
// ONLY {v_pk_fma_f32, v_pk_mul_f32, v_pk_add_f32} — no v_pk_max_f32.
__device__ __forceinline__ v2f pk_add(v2f a, v2f b) {
    v2f d;
    asm("v_pk_add_f32 %0, %1, %2" : "=v"(d) : "v"(a), "v"(b));
    return d;
}
// lo(a) broadcast to both lanes; b,c normal
__device__ __forceinline__ v2f pk_fma_blo(v2f a, v2f b, v2f c) {
    v2f d;
    asm("v_pk_fma_f32 %0, %1, %2, %3 op_sel:[0,0,0] op_sel_hi:[0,1,1]"
        : "=v"(d) : "v"(a), "v"(b), "v"(c));
    return d;
}
// hi(a) broadcast; b,c normal
__device__ __forceinline__ v2f pk_fma_bhi(v2f a, v2f b, v2f c) {
    v2f d;
    asm("v_pk_fma_f32 %0, %1, %2, %3 op_sel:[1,0,0] op_sel_hi:[1,1,1]"
        : "=v"(d) : "v"(a), "v"(b), "v"(c));
    return d;
}
// lo(a) broadcast AND hi(c) broadcast; b normal   (a.lo*b + c.hi per lane)
__device__ __forceinline__ v2f pk_fma_blo_chi(v2f a, v2f b, v2f c) {
    v2f d;
    asm("v_pk_fma_f32 %0, %1, %2, %3 op_sel:[0,0,1] op_sel_hi:[0,1,1]"
        : "=v"(d) : "v"(a), "v"(b), "v"(c));
    return d;
}
// a + hi(b) broadcast
__device__ __forceinline__ v2f pk_add_bhi(v2f a, v2f b) {
    v2f d;
    asm("v_pk_add_f32 %0, %1, %2 op_sel:[0,1] op_sel_hi:[1,1]"
        : "=v"(d) : "v"(a), "v"(b));
    return d;
}

// accumulator slots (floats) at start of workspace
constexpr int A_SSIMA  = 0;   // [B]
constexpr int A_SSIMB  = 2;   // [B]
constexpr int A_SSIMC  = 4;   // [B]
constexpr int A_CH1    = 6;
constexpr int A_CH2    = 7;
constexpr int A_AUX    = 8;
constexpr int A_INT    = 9;
constexpr int A_LOUT   = 10;  // [B]
constexpr int A_CNT    = 12;  // [B]
constexpr int A_SMOOTH = 14;
constexpr int A_SINK   = 16;  // [6]
constexpr int A_MAX    = 32;  // 8 uint slots (4 fields x B), float-bits
constexpr int A_DONE   = 40;  // uint: last-block-done counter for val+finalize

// ---------------- block reduction helpers (blockDim == 256) ----------------
__device__ __forceinline__ float blockSum(float v, int tid) {
#pragma unroll
    for (int o = 32; o; o >>= 1) v += __shfl_down(v, o, 64);
    __shared__ float sh[4];
    __syncthreads();
    if ((tid & 63) == 0) sh[tid >> 6] = v;
    __syncthreads();
    return sh[0] + sh[1] + sh[2] + sh[3];
}

__device__ __forceinline__ float blockMax(float v, int tid) {
#pragma unroll
    for (int o = 32; o; o >>= 1) v = fmaxf(v, __shfl_down(v, o, 64));
    __shared__ float sh[4];
    __syncthreads();
    if ((tid & 63) == 0) sh[tid >> 6] = v;
    __syncthreads();
    return fmaxf(fmaxf(sh[0], sh[1]), fmaxf(sh[2], sh[3]));
}

// -------- fused prep (y_gray, intensity, L_out, cnt) + avgpool2 + gather ----
// grid (336, 2): x<256 prep, x<320 pool, else gather (16 blocks per y-slice)
__global__ __launch_bounds__(256) void egf_prep_pool(const float* __restrict__ y,
                                                     const float* __restrict__ pet,
                                                     const float* __restrict__ mri,
                                                     const float* __restrict__ mask,
                                                     const int* __restrict__ idx,
                                                     float* __restrict__ ygray,
                                                     float* __restrict__ py,
                                                     float* __restrict__ pmri,
                                                     float4* __restrict__ pts,
                                                     float* __restrict__ acc) {
    int b = blockIdx.y;
    if (blockIdx.x < 256) {
        int p = blockIdx.x * 256 + threadIdx.x;      // exactly 65536
        float m  = mask[b * 65536 + p];
        float y0 = y[(b * 3 + 0) * 65536 + p];
        float y1 = y[(b * 3 + 1) * 65536 + p];
        float y2 = y[(b * 3 + 2) * 65536 + p];
        float q0 = pet[(b * 3 + 0) * 65536 + p];
        float q1 = pet[(b * 3 + 1) * 65536 + p];
        float q2 = pet[(b * 3 + 2) * 65536 + p];
        ygray[b * 65536 + p] = (y0 + y1 + y2) * (1.0f / 3.0f);
        float d0 = m * y0 - m * q0, d1 = m * y1 - m * q1, d2 = m * y2 - m * q2;
        float inten = d0 * d0 + d1 * d1 + d2 * d2;
        float im = 1.0f - m;
        float o0 = y0 * im, o1 = y1 * im, o2 = y2 * im;
        float lout = o0 * o0 + o1 * o1 + o2 * o2;
        float cnt = (m > 0.1f) ? 1.0f : 0.0f;
        float t;
        t = blockSum(inten, threadIdx.x); if (threadIdx.x == 0) atomicAdd(&acc[A_INT], t);
        t = blockSum(lout,  threadIdx.x); if (threadIdx.x == 0) atomicAdd(&acc[A_LOUT + b], t);
        t = blockSum(cnt,   threadIdx.x); if (threadIdx.x == 0) atomicAdd(&acc[A_CNT + b], t);
    } else if (blockIdx.x < 320) {
        int po = (blockIdx.x - 256) * 256 + threadIdx.x;  // exactly 16384
        int i = po >> 7, j = po & 127;
        int p0 = (i * 2) * 256 + j * 2;
        float s = 0.0f;
#pragma unroll
        for (int c = 0; c < 3; c++) {
            const float* ip = y + (b * 3 + c) * 65536;
            s += ip[p0] + ip[p0 + 1] + ip[p0 + 256] + ip[p0 + 257];
        }
        py[b * 16384 + po] = s * (1.0f / 12.0f);
        const float* mp = mri + b * 65536;
        pmri[b * 16384 + po] = (mp[p0] + mp[p0 + 1] + mp[p0 + 256] + mp[p0 + 257]) * 0.25f;
    } else {
        // gather masked point clouds (independent of everything above)
        int t = (b * 16 + (blockIdx.x - 320)) * 256 + threadIdx.x;   // < 8192
        int bb = t >> 12, j = t & 4095;
        int p = idx[bb * 4096 + j];
        float m = mask[bb * 65536 + p];
        float a0 = y[(bb * 3 + 0) * 65536 + p] * m;
        float a1 = y[(bb * 3 + 1) * 65536 + p] * m;
        float a2 = y[(bb * 3 + 2) * 65536 + p] * m;
        pts[(bb * 2 + 0) * 4096 + j] = make_float4(a0, a1, a2, 0.5f * (a0 * a0 + a1 * a1 + a2 * a2));
        float c0 = pet[(bb * 3 + 0) * 65536 + p] * m;
        float c1 = pet[(bb * 3 + 1) * 65536 + p] * m;
        float c2 = pet[(bb * 3 + 2) * 65536 + p] * m;
        pts[(bb * 2 + 1) * 4096 + j] = make_float4(c0, c1, c2, 0.5f * (c0 * c0 + c1 * c1 + c2 * c2));
    }
}

// ---------------- 4 sobel passes fused (grid.x partitions the 4 images) -----
__global__ __launch_bounds__(256) void egf_sobel4(const float* __restrict__ yg,
                                                  const float* __restrict__ mri,
                                                  const float* __restrict__ py,
                                                  const float* __restrict__ pmri,
                                                  float* __restrict__ mag_yg,
                                                  float* __restrict__ mag_mri,
                                                  float* __restrict__ mag_py,
                                                  float* __restrict__ mag_pmri,
                                                  unsigned* __restrict__ mx) {
    int b = blockIdx.y;
    int x = blockIdx.x;
    const float* in; float* mag; int H, logH, slot, p;
    if (x < 256)      { in = yg;   mag = mag_yg;   H = 256; logH = 8; slot = 0; p = x * 256 + threadIdx.x; }
    else if (x < 512) { in = mri;  mag = mag_mri;  H = 256; logH = 8; slot = 2; p = (x - 256) * 256 + threadIdx.x; }
    else if (x < 576) { in = py;   mag = mag_py;   H = 128; logH = 7; slot = 4; p = (x - 512) * 256 + threadIdx.x; }
    else              { in = pmri; mag = mag_pmri; H = 128; logH = 7; slot = 6; p = (x - 576) * 256 + threadIdx.x; }
    int HH = H * H;
    const float* ip = in + b * HH;
    int i = p >> logH, j = p & (H - 1);
    auto at = [&](int ii, int jj) -> float {
        return (ii >= 0 && ii < H && jj >= 0 && jj < H) ? ip[(ii << logH) + jj] : 0.0f;
    };
    float a00 = at(i - 1, j - 1), a01 = at(i - 1, j), a02 = at(i - 1, j + 1);
    float a10 = at(i, j - 1),                         a12 = at(i, j + 1);
    float a20 = at(i + 1, j - 1), a21 = at(i + 1, j), a22 = at(i + 1, j + 1);
    float gx = a00 - a02 + 2.0f * a10 - 2.0f * a12 + a20 - a22;
    float gy = a00 + 2.0f * a01 + a02 - a20 - 2.0f * a21 - a22;
    float m = sqrtf(gx * gx + gy * gy + 1e-6f);
    mag[b * HH + p] = m;
    float bm = blockMax(m, threadIdx.x);
    if (threadIdx.x == 0) atomicMax(mx + slot + b, __float_as_uint(bm));
}

// ---------------- 2 charbonnier passes fused ----------------
__global__ __launch_bounds__(256) void egf_charb2(const float* __restrict__ mag_yg,
                                                  const float* __restrict__ mag_mri,
                                                  const float* __restrict__ mag_py,
                                                  const float* __restrict__ mag_pmri,
                                                  const unsigned* __restrict__ mx,
                                                  const float* __restrict__ ehat,
                                                  float* __restrict__ acc) {
    int b = blockIdx.y;
    int x = blockIdx.x;
    const float *magA, *magB; const unsigned *mxA, *mxB;
    float *accC; const float* eh; int HH, p;
    if (x < 256) { magA = mag_yg; magB = mag_mri; mxA = mx + 0; mxB = mx + 2;
                   accC = acc + A_CH1; eh = ehat; HH = 65536; p = x * 256 + threadIdx.x; }
    else         { magA = mag_py; magB = mag_pmri; mxA = mx + 4; mxB = mx + 6;
                   accC = acc + A_CH2; eh = nullptr; HH = 16384; p = (x - 256) * 256 + threadIdx.x; }
    float c = 0.0f, au = 0.0f;
    float da = fmaxf(__uint_as_float(mxA[b]), 1e-6f);
    float db = fmaxf(__uint_as_float(mxB[b]), 1e-6f);
    if (p < HH) {
        float sa = magA[b * HH + p] / da;
        float sb = magB[b * HH + p] / db;
        float d = sa - sb;
        c = sqrtf(d * d + 1e-6f);
        if (eh) au = fabsf(eh[b * HH + p] - sb);
    }
    float tc = blockSum(c, threadIdx.x);
    if (threadIdx.x == 0) atomicAdd(accC, tc);
    if (eh) {
        float ta = blockSum(au, threadIdx.x);
        if (threadIdx.x == 0) atomicAdd(&acc[A_AUX], ta);
    }
}

// ------- SSIM, SEPARABLE: vertical 11-tap -> 5 LDS planes -> horizontal -----
// 3 configs fused via z (z<2: yg/mri, <8: y/pet, else masked y/mri)
__global__ __launch_bounds__(256) void egf_ssim3(const float* __restrict__ y,
                                                 const float* __restrict__ ygray,
                                                 const float* __restrict__ mri,
                                                 const float* __restrict__ pet,
                                                 const float* __restrict__ mask,
                                                 float* __restrict__ acc) {
    int z = blockIdx.z;
    const float *xp, *yp, *mp = nullptr; float* accB; int b;
    if (z < 2) {
        b = z; xp = ygray + b * 65536; yp = mri + b * 65536; accB = acc + A_SSIMA;
    } else if (z < 8) {
        int bc = z - 2; b = bc / 3; int c = bc - b * 3;
        xp = y + (b * 3 + c) * 65536; yp = pet + (b * 3 + c) * 65536; accB = acc + A_SSIMB;
    } else {
        int bc = z - 8; b = bc / 3; int c = bc - b * 3;
        xp = y + (b * 3 + c) * 65536; yp = mri + b * 65536; mp = mask + b * 65536; accB = acc + A_SSIMC;
    }
    __shared__ float sx[26][27];
    __shared__ float sy[26][27];
    __shared__ float va[16][27];   // vert-filtered x
    __shared__ float vb[16][27];   // vert-filtered y
    __shared__ float vc[16][27];   // vert-filtered x*x
    __shared__ float vd[16][27];   // vert-filtered y*y
    __shared__ float ve[16][27];   // vert-filtered x*y
    int ti = blockIdx.x * 16, tj = blockIdx.y * 16;
    int tid = threadIdx.y * 16 + threadIdx.x;
    for (int t = tid; t < 26 * 26; t += 256) {
        int li = t / 26, lj = t - li * 26;
        int gi = ti + li, gj = tj + lj;
        float a = 0.0f, bb = 0.0f;
        if (gi < 256 && gj < 256) {
            int p = (gi << 8) + gj;
            float m = mp ? mp[p] : 1.0f;
            a = xp[p] * m; bb = yp[p] * m;
        }
        sx[li][lj] = a; sy[li][lj] = bb;
    }
    float w[11];
    {
        float s = 0.0f;
#pragma unroll
        for (int i = 0; i < 11; i++) { float d = (float)(i - 5); w[i] = expf(-d * d * (1.0f / 4.5f)); s += w[i]; }
        float inv = 1.0f / s;
#pragma unroll
        for (int i = 0; i < 11; i++) w[i] *= inv;
    }
    __syncthreads();
    // vertical pass: 16 output rows x 26 cols
    for (int t = tid; t < 16 * 26; t += 256) {
        int r = t / 26, c = t - r * 26;
        float s0 = 0, s1 = 0, s2 = 0, s3 = 0, s4 = 0;
#pragma unroll
        for (int k = 0; k < 11; k++) {
            float wk = w[k];
            float a = sx[r + k][c], bb = sy[r + k][c];
            s0 += wk * a; s1 += wk * bb;
            s2 += wk * a * a; s3 += wk * bb * bb; s4 += wk * a * bb;
        }
        va[r][c] = s0; vb[r][c] = s1; vc[r][c] = s2; vd[r][c] = s3; ve[r][c] = s4;
    }
    __syncthreads();
    // horizontal pass: one output per thread
    int oi = ti + threadIdx.y, oj = tj + threadIdx.x;
    float val = 0.0f;
    if (oi < 246 && oj < 246) {
        float mu1 = 0, mu2 = 0, xx = 0, yy = 0, xy = 0;
        int ty = threadIdx.y, tx = threadIdx.x;
#pragma unroll
        for (int k = 0; k < 11; k++) {
            float wk = w[k];
            mu1 += wk * va[ty][tx + k]; mu2 += wk * vb[ty][tx + k];
            xx  += wk * vc[ty][tx + k]; yy  += wk * vd[ty][tx + k];
            xy  += wk * ve[ty][tx + k];
        }
        float s11 = xx - mu1 * mu1, s22 = yy - mu2 * mu2, s12 = xy - mu1 * mu2;
        const float C1 = 1e-4f, C2 = 9e-4f;
        val = ((2.0f * mu1 * mu2 + C1) * (2.0f * s12 + C2)) /
              ((mu1 * mu1 + mu2 * mu2 + C1) * (s11 + s22 + C2));
    }
    float tot = blockSum(val, tid);
    if (tid == 0) atomicAdd(&accB[b], tot);
}

// ---------------- gaussian smooth, one-pass LDS-tiled ----------------
__device__ __forceinline__ int refl256(int i) { return i < 0 ? -1 - i : (i > 255 ? 511 - i : i); }

__device__ __forceinline__ void gauss9(float* w) {
    float s = 0.0f;
#pragma unroll
    for (int t = 0; t < 9; t++) { float d = (float)(t - 4); w[t] = expf(-0.5f * d * d); s += w[t]; }
    float inv = 1.0f / s;
#pragma unroll
    for (int t = 0; t < 9; t++) w[t] *= inv;
}

__global__ __launch_bounds__(256) void egf_smooth1(const float* __restrict__ y,
                                                   float* __restrict__ acc) {
    int bc = blockIdx.z;
    int i0 = blockIdx.x * 16, j0 = blockIdx.y * 16;
    const float* ip = y + bc * 65536;
    __shared__ float sx[24][25];
    __shared__ float sv[16][25];
    int tid = threadIdx.x;
    float w[9]; gauss9(w);
    for (int t = tid; t < 576; t += 256) {
        int li = t / 24, lj = t - li * 24;
        int gi = refl256(i0 + li - 4), gj = refl256(j0 + lj - 4);
        sx[li][lj] = ip[(gi << 8) + gj];
    }
    __syncthreads();
    for (int t = tid; t < 384; t += 256) {
        int li = t / 24, lj = t - li * 24;     // li in [0,16), lj in [0,24)
        float s = 0.0f;
#pragma unroll
        for (int k = 0; k < 9; k++) s += w[k] * sx[li + k][lj];
        sv[li][lj] = s;
    }
    __syncthreads();
    int ty = tid >> 4, tx = tid & 15;
    float s = 0.0f;
#pragma unroll
    for (int k = 0; k < 9; k++) s += w[k] * sv[ty][tx + k];
    float d = s - sx[ty + 4][tx + 4];
    float tt = blockSum(d * d, tid);
    if (tid == 0) atomicAdd(acc, tt);
}

// ------ fused combine (staging) helper, NCH=64, SINGLE-FLOAT lse partials ---
// partial[chunk][col] = log2( sum_r exp2(e_r - b_c) )  (per 64-row chunk).
// Combine: M = max_k lse_k; S = sum_k exp2(lse_k - M)  — exact LSE merge.
__device__ __forceinline__ float stageCombine(const float* __restrict__ Pin,
                                              int qbase, int row, int h, int r_local,
                                              float* sm, float* ss, int tid) {
    const float* p = Pin + qbase + (h * 16) * NPTS + row;
    float t[16];
#pragma unroll
    for (int k = 0; k < 16; k++) t[k] = p[k * NPTS];
    float m16 = -3.4e38f;
#pragma unroll
    for (int k = 0; k < 16; k++) m16 = fmaxf(m16, t[k]);
    float s16 = 0.0f;
#pragma unroll
    for (int k = 0; k < 16; k++) s16 += __builtin_amdgcn_exp2f(t[k] - m16);
    sm[h * 64 + r_local] = m16;
    ss[h * 64 + r_local] = s16;
    __syncthreads();
    float v = 0.0f;
    if (tid < 64) {
        float m0 = sm[tid], m1 = sm[64 + tid], m2 = sm[128 + tid], m3 = sm[192 + tid];
        float M = fmaxf(fmaxf(m0, m1), fmaxf(m2, m3));
        float S = ss[tid]       * __builtin_amdgcn_exp2f(m0 - M) +
                  ss[64 + tid]  * __builtin_amdgcn_exp2f(m1 - M) +
                  ss[128 + tid] * __builtin_amdgcn_exp2f(m2 - M) +
                  ss[192 + tid] * __builtin_amdgcn_exp2f(m3 - M);
        v = EPS_LOGN - EPS_LN2 * (M + log2f(S));
    }
    return v;
}

// ---------------- sinkhorn half: two-pass (VERIFIED core), CHUNK=64 ---------
// Only the partial STORE format changed: lse = m - b_c + log2(s), one float.
__global__ __launch_bounds__(256) void egf_sink_half8(const float4* __restrict__ pts,
                                                      const float* __restrict__ Pin,
                                                      float* __restrict__ Pout,
                                                      int dir, int init) {
    int q = blockIdx.z; int b = q / 3, t = q - b * 3;
    int xsel = (t == 2) ? 1 : 0;
    int ysel = (t == 1) ? 0 : 1;
    const float4* rowP = pts + (b * 2 + (dir ? ysel : xsel)) * NPTS;
    const float4* colP = pts + (b * 2 + (dir ? xsel : ysel)) * NPTS;

    __shared__ float4 srow[CHUNK];
    __shared__ float sm[256], ss[256];
    int tid = threadIdx.x;
    int chunk = blockIdx.y;
    int r_local = tid & 63, h = tid >> 6;
    int row = chunk * CHUNK + r_local;

    // prefetch column fragments (independent of the staging barrier)
    int col0 = blockIdx.x * COLS_PER_BLK + tid;
    float4 cf[8];
#pragma unroll
    for (int k = 0; k < 8; k++) cf[k] = colP[col0 + k * 256];

    float v = 0.0f;
    if (!init)
        v = stageCombine(Pin, q * QSTRIDE, row, h, r_local, sm, ss, tid);
    if (tid < 64) {
        float4 pp = rowP[row];
        srow[tid] = make_float4(pp.x * INV_EPS_L2E, pp.y * INV_EPS_L2E,
                                pp.z * INV_EPS_L2E, (v - pp.w) * INV_EPS_L2E);
    }
    __syncthreads();

    v2f cx[4], cy[4], cz[4], cw[4];
#pragma unroll
    for (int p = 0; p < 4; p++) {
        cx[p] = (v2f){cf[2 * p].x, cf[2 * p + 1].x};
        cy[p] = (v2f){cf[2 * p].y, cf[2 * p + 1].y};
        cz[p] = (v2f){cf[2 * p].z, cf[2 * p + 1].z};
        cw[p] = (v2f){cf[2 * p].w * INV_EPS_L2E, cf[2 * p + 1].w * INV_EPS_L2E};
    }
    v2f mx[4];
#pragma unroll
    for (int p = 0; p < 4; p++) mx[p] = (v2f){-3.4e38f, -3.4e38f};
#pragma unroll 4
    for (int rr = 0; rr < CHUNK; rr++) {
        float4 rp = srow[rr];
        v2f rxy = (v2f){rp.x, rp.y};
        v2f rzw = (v2f){rp.z, rp.w};
#pragma unroll
        for (int p = 0; p < 4; p++) {
            v2f e = pk_fma_blo_chi(rzw, cz[p], rzw);   // Z*cz + W
            e = pk_fma_bhi(rxy, cy[p], e);             // + Y*cy
            e = pk_fma_blo(rxy, cx[p], e);             // + X*cx
            mx[p].x = fmaxf(mx[p].x, e.x);
            mx[p].y = fmaxf(mx[p].y, e.y);
        }
    }
    v2f mneg[4], sa[4];
#pragma unroll
    for (int p = 0; p < 4; p++) { mneg[p] = -mx[p]; sa[p] = (v2f){0.0f, 0.0f}; }
#pragma unroll 4
    for (int rr = 0; rr < CHUNK; rr++) {
        float4 rp = srow[rr];
        v2f rxy = (v2f){rp.x, rp.y};
        v2f rzw = (v2f){rp.z, rp.w};
#pragma unroll
        for (int p = 0; p < 4; p++) {
            v2f e = pk_fma_blo(rzw, cz[p], mneg[p]);   // Z*cz - mx
            e = pk_fma_bhi(rxy, cy[p], e);             // + Y*cy
            e = pk_fma_blo(rxy, cx[p], e);             // + X*cx
            e = pk_add_bhi(e, rzw);                    // + W
            v2f ex;
            ex.x = __builtin_amdgcn_exp2f(e.x);
            ex.y = __builtin_amdgcn_exp2f(e.y);
            sa[p] = pk_add(sa[p], ex);
        }
    }
    float* om = Pout + q * QSTRIDE + chunk * NPTS;
#pragma unroll
    for (int p = 0; p < 4; p++) {
        om[col0 + (2 * p) * 256]     = mx[p].x - cw[p].x + log2f(sa[p].x);
        om[col0 + (2 * p + 1) * 256] = mx[p].y - cw[p].y + log2f(sa[p].y);
    }
}

// ---------------- final scalar assembly (device helper) ----------------
__device__ __forceinline__ void finalize_body(float* acc, float* out) {
    auto rd = [&](int i) -> float { return atomicAdd(&acc[i], 0.0f); };
    const float AREA = 246.0f * 246.0f;
    float ssim_m = 1.0f - (rd(A_SSIMA) + rd(A_SSIMA + 1)) / (2.0f * AREA);
    float ssim_p = 1.0f - (rd(A_SSIMB) + rd(A_SSIMB + 1)) / (2.0f * 3.0f * AREA);
    float g_cons = rd(A_CH1) / (2.0f * 65536.0f) + rd(A_CH2) / (2.0f * 16384.0f);
    float aux = rd(A_AUX) / (2.0f * 65536.0f);
    float inc0 = (rd(A_CNT)     >= 31.5f) ? 1.0f : 0.0f;
    float inc1 = (rd(A_CNT + 1) >= 31.5f) ? 1.0f : 0.0f;
    float v0 = rd(A_SINK + 0), v1 = rd(A_SINK + 1), v2 = rd(A_SINK + 2);
    float v3 = rd(A_SINK + 3), v4 = rd(A_SINK + 4), v5 = rd(A_SINK + 5);
    float Lt = (inc0 * (v0 - 0.5f * v1 - 0.5f * v2) +
                inc1 * (v3 - 0.5f * v4 - 0.5f * v5)) * 0.5f;
    float Lo = (inc0 * rd(A_LOUT) + inc1 * rd(A_LOUT + 1)) / (3.0f * 65536.0f) * 0.5f;
    float Ls = (inc0 * (1.0f - rd(A_SSIMC) / (3.0f * AREA)) +
                inc1 * (1.0f - rd(A_SSIMC + 1) / (3.0f * AREA))) * 0.5f;
    float Li = 2.5f * rd(A_INT) / (2.0f * 3.0f * 65536.0f);
    float Lsm = rd(A_SMOOTH) / (2.0f * 3.0f * 65536.0f);
    float total = 0.8f * Lt + 0.3f * Lo + 0.5f * Ls + Li + 0.2f * Lsm;
    out[0] = total; out[1] = ssim_m; out[2] = ssim_p; out[3] = g_cons; out[4] = aux;
}

// ---------------- sinkhorn value + last-block finalize ----------------
// grid (128, 6): blockIdx.x>>6 selects f/g partials, &63 selects the 64-row chunk.
__global__ __launch_bounds__(256) void egf_sink_val8(const float* __restrict__ Pf,
                                                     const float* __restrict__ Pg,
                                                     float* __restrict__ acc,
                                                     float* __restrict__ out) {
    int q = blockIdx.y;
    int side = blockIdx.x >> 6;
    int chunk = blockIdx.x & 63;
    const float* P = side ? Pg : Pf;
    __shared__ float sm[256], ss[256];
    int tid = threadIdx.x;
    int r_local = tid & 63, h = tid >> 6;
    int row = chunk * CHUNK + r_local;
    float v = stageCombine(P, q * QSTRIDE, row, h, r_local, sm, ss, tid);
    float tot = blockSum(v, tid);
    if (tid == 0) {
        atomicAdd(&acc[A_SINK + q], tot * (1.0f / 4096.0f));
        __threadfence();
        unsigned old = atomicAdd((unsigned*)&acc[A_DONE], 1u);
        if (old == 128u * 6u - 1u) finalize_body(acc, out);   // last block finalizes
    }
}

// ---------------- host launch ----------------
extern "C" void kernel_launch(void* const* d_in, const int* in_sizes, int n_in,
                              void* d_out, int out_size, void* d_ws, size_t ws_size,
                              hipStream_t stream) {
    const float* y    = (const float*)d_in[0];
    const float* mri  = (const float*)d_in[1];
    const float* pet  = (const float*)d_in[2];
    const float* mask = (const float*)d_in[3];
    const float* ehat = (const float*)d_in[4];
    const int*   idx  = (const int*)d_in[5];
    float* out = (float*)d_out;
    float* ws  = (float*)d_ws;

    float* acc   = ws;                    // 64 floats
    float4* pts  = (float4*)(ws + 64);    // 4*4096 float4 = 65536 floats
    float* base  = ws + 64 + 65536;

    // sinkhorn partials: 2 float planes of 6*64*4096 elements (6.3 MB apiece)
    float* Pf = base;
    float* Pg = Pf + QSTRIDE * 6;
    float* ibase = base + 2 * QSTRIDE * 6;

    // image scratch
    float* ygray    = ibase;              // 131072
    float* py       = ygray + 131072;     // 32768
    float* pmri     = py + 32768;         // 32768
    float* mag_yg   = pmri + 32768;       // 131072
    float* mag_mri  = mag_yg + 131072;    // 131072
    float* mag_py   = mag_mri + 131072;   // 32768
    float* mag_pmri = mag_py + 32768;     // 32768

    hipMemsetAsync(acc, 0, 64 * sizeof(float), stream);

    unsigned* mx = (unsigned*)(acc + A_MAX);

    egf_prep_pool<<<dim3(336, 2), 256, 0, stream>>>(y, pet, mri, mask, idx,
                                                    ygray, py, pmri, pts, acc);
    egf_sobel4<<<dim3(640, 2), 256, 0, stream>>>(ygray, mri, py, pmri,
                                                 mag_yg, mag_mri, mag_py, mag_pmri, mx);
    egf_charb2<<<dim3(320, 2), 256, 0, stream>>>(mag_yg, mag_mri, mag_py, mag_pmri, mx, ehat, acc);
    egf_ssim3<<<dim3(16, 16, 14), dim3(16, 16), 0, stream>>>(y, ygray, mri, pet, mask, acc);
    egf_smooth1<<<dim3(16, 16, 6), 256, 0, stream>>>(y, acc + A_SMOOTH);

    dim3 sgrid(NCB, NCH, 6);   // 2 x 64 x 6 = 768 blocks
    for (int it = 0; it < 11; ++it) {
        egf_sink_half8<<<sgrid, 256, 0, stream>>>(pts, Pf, Pg, 0, it == 0 ? 1 : 0);
        egf_sink_half8<<<sgrid, 256, 0, stream>>>(pts, Pg, Pf, 1, 0);
    }
    egf_sink_val8<<<dim3(128, 6), 256, 0, stream>>>(Pf, Pg, acc, out);
}

// Round 9
// 746.771 us; speedup vs baseline: 1.1301x; 1.0507x over previous
//
#include <hip/hip_runtime.h>
#include <math.h>

// ---------------- constants ----------------
#define INV_EPS_L2E 577.0780163555854f   // (1/eps) * log2(e) = 1/(eps*ln2)
#define EPS_LOGN 0.02079441542f          // eps * ln(4096) = -eps*loga
#define EPS_LN2 0.00173286795f           // eps * ln(2)

#define NPTS 4096
#define CHUNK 64
#define NCH 64            // 4096/64
#define CPT 8             // columns per thread (4 packed pairs)
#define COLS_PER_BLK 2048 // 256*CPT
#define NCB 2             // 4096/2048
#define QSTRIDE (NCH * NPTS)  // float elements per problem in partial arrays (lse format)

typedef float v2f __attribute__((ext_vector_type(2)));

// True packed-fp32 ops with VOP3P op_sel broadcasts. gfx950 packed-f32 set is
// ONLY {v_pk_fma_f32, v_pk_mul_f32, v_pk_add_f32} — no v_pk_max_f32.
__device__ __forceinline__ v2f pk_add(v2f a, v2f b) {
    v2f d;
    asm("v_pk_add_f32 %0, %1, %2" : "=v"(d) : "v"(a), "v"(b));
    return d;
}
// lo(a) broadcast to both lanes; b,c normal
__device__ __forceinline__ v2f pk_fma_blo(v2f a, v2f b, v2f c) {
    v2f d;
    asm("v_pk_fma_f32 %0, %1, %2, %3 op_sel:[0,0,0] op_sel_hi:[0,1,1]"
        : "=v"(d) : "v"(a), "v"(b), "v"(c));
    return d;
}
// hi(a) broadcast; b,c normal
__device__ __forceinline__ v2f pk_fma_bhi(v2f a, v2f b, v2f c) {
    v2f d;
    asm("v_pk_fma_f32 %0, %1, %2, %3 op_sel:[1,0,0] op_sel_hi:[1,1,1]"
        : "=v"(d) : "v"(a), "v"(b), "v"(c));
    return d;
}
// lo(a) broadcast AND hi(c) broadcast; b normal   (a.lo*b + c.hi per lane)
__device__ __forceinline__ v2f pk_fma_blo_chi(v2f a, v2f b, v2f c) {
    v2f d;
    asm("v_pk_fma_f32 %0, %1, %2, %3 op_sel:[0,0,1] op_sel_hi:[0,1,1]"
        : "=v"(d) : "v"(a), "v"(b), "v"(c));
    return d;
}
// a + hi(b) broadcast
__device__ __forceinline__ v2f pk_add_bhi(v2f a, v2f b) {
    v2f d;
    asm("v_pk_add_f32 %0, %1, %2 op_sel:[0,1] op_sel_hi:[1,1]"
        : "=v"(d) : "v"(a), "v"(b));
    return d;
}

// accumulator slots (floats) at start of workspace
constexpr int A_SSIMA  = 0;   // [B]
constexpr int A_SSIMB  = 2;   // [B]
constexpr int A_SSIMC  = 4;   // [B]
constexpr int A_CH1    = 6;
constexpr int A_CH2    = 7;
constexpr int A_AUX    = 8;
constexpr int A_INT    = 9;
constexpr int A_LOUT   = 10;  // [B]
constexpr int A_CNT    = 12;  // [B]
constexpr int A_SMOOTH = 14;
constexpr int A_SINK   = 16;  // [6]
constexpr int A_MAX    = 32;  // 8 uint slots (4 fields x B), float-bits
constexpr int A_DONE   = 40;  // uint: last-block-done counter for val+finalize

// ---------------- block reduction helpers (blockDim == 256) ----------------
__device__ __forceinline__ float blockSum(float v, int tid) {
#pragma unroll
    for (int o = 32; o; o >>= 1) v += __shfl_down(v, o, 64);
    __shared__ float sh[4];
    __syncthreads();
    if ((tid & 63) == 0) sh[tid >> 6] = v;
    __syncthreads();
    return sh[0] + sh[1] + sh[2] + sh[3];
}

__device__ __forceinline__ float blockMax(float v, int tid) {
#pragma unroll
    for (int o = 32; o; o >>= 1) v = fmaxf(v, __shfl_down(v, o, 64));
    __shared__ float sh[4];
    __syncthreads();
    if ((tid & 63) == 0) sh[tid >> 6] = v;
    __syncthreads();
    return fmaxf(fmaxf(sh[0], sh[1]), fmaxf(sh[2], sh[3]));
}

// -------- fused prep (y_gray, intensity, L_out, cnt) + avgpool2 + gather ----
// grid (336, 2): x<256 prep, x<320 pool, else gather (16 blocks per y-slice)
__global__ __launch_bounds__(256) void egf_prep_pool(const float* __restrict__ y,
                                                     const float* __restrict__ pet,
                                                     const float* __restrict__ mri,
                                                     const float* __restrict__ mask,
                                                     const int* __restrict__ idx,
                                                     float* __restrict__ ygray,
                                                     float* __restrict__ py,
                                                     float* __restrict__ pmri,
                                                     float4* __restrict__ pts,
                                                     float* __restrict__ acc) {
    int b = blockIdx.y;
    if (blockIdx.x < 256) {
        int p = blockIdx.x * 256 + threadIdx.x;      // exactly 65536
        float m  = mask[b * 65536 + p];
        float y0 = y[(b * 3 + 0) * 65536 + p];
        float y1 = y[(b * 3 + 1) * 65536 + p];
        float y2 = y[(b * 3 + 2) * 65536 + p];
        float q0 = pet[(b * 3 + 0) * 65536 + p];
        float q1 = pet[(b * 3 + 1) * 65536 + p];
        float q2 = pet[(b * 3 + 2) * 65536 + p];
        ygray[b * 65536 + p] = (y0 + y1 + y2) * (1.0f / 3.0f);
        float d0 = m * y0 - m * q0, d1 = m * y1 - m * q1, d2 = m * y2 - m * q2;
        float inten = d0 * d0 + d1 * d1 + d2 * d2;
        float im = 1.0f - m;
        float o0 = y0 * im, o1 = y1 * im, o2 = y2 * im;
        float lout = o0 * o0 + o1 * o1 + o2 * o2;
        float cnt = (m > 0.1f) ? 1.0f : 0.0f;
        float t;
        t = blockSum(inten, threadIdx.x); if (threadIdx.x == 0) atomicAdd(&acc[A_INT], t);
        t = blockSum(lout,  threadIdx.x); if (threadIdx.x == 0) atomicAdd(&acc[A_LOUT + b], t);
        t = blockSum(cnt,   threadIdx.x); if (threadIdx.x == 0) atomicAdd(&acc[A_CNT + b], t);
    } else if (blockIdx.x < 320) {
        int po = (blockIdx.x - 256) * 256 + threadIdx.x;  // exactly 16384
        int i = po >> 7, j = po & 127;
        int p0 = (i * 2) * 256 + j * 2;
        float s = 0.0f;
#pragma unroll
        for (int c = 0; c < 3; c++) {
            const float* ip = y + (b * 3 + c) * 65536;
            s += ip[p0] + ip[p0 + 1] + ip[p0 + 256] + ip[p0 + 257];
        }
        py[b * 16384 + po] = s * (1.0f / 12.0f);
        const float* mp = mri + b * 65536;
        pmri[b * 16384 + po] = (mp[p0] + mp[p0 + 1] + mp[p0 + 256] + mp[p0 + 257]) * 0.25f;
    } else {
        // gather masked point clouds (independent of everything above)
        int t = (b * 16 + (blockIdx.x - 320)) * 256 + threadIdx.x;   // < 8192
        int bb = t >> 12, j = t & 4095;
        int p = idx[bb * 4096 + j];
        float m = mask[bb * 65536 + p];
        float a0 = y[(bb * 3 + 0) * 65536 + p] * m;
        float a1 = y[(bb * 3 + 1) * 65536 + p] * m;
        float a2 = y[(bb * 3 + 2) * 65536 + p] * m;
        pts[(bb * 2 + 0) * 4096 + j] = make_float4(a0, a1, a2, 0.5f * (a0 * a0 + a1 * a1 + a2 * a2));
        float c0 = pet[(bb * 3 + 0) * 65536 + p] * m;
        float c1 = pet[(bb * 3 + 1) * 65536 + p] * m;
        float c2 = pet[(bb * 3 + 2) * 65536 + p] * m;
        pts[(bb * 2 + 1) * 4096 + j] = make_float4(c0, c1, c2, 0.5f * (c0 * c0 + c1 * c1 + c2 * c2));
    }
}

// ---------------- 4 sobel passes fused (grid.x partitions the 4 images) -----
__global__ __launch_bounds__(256) void egf_sobel4(const float* __restrict__ yg,
                                                  const float* __restrict__ mri,
                                                  const float* __restrict__ py,
                                                  const float* __restrict__ pmri,
                                                  float* __restrict__ mag_yg,
                                                  float* __restrict__ mag_mri,
                                                  float* __restrict__ mag_py,
                                                  float* __restrict__ mag_pmri,
                                                  unsigned* __restrict__ mx) {
    int b = blockIdx.y;
    int x = blockIdx.x;
    const float* in; float* mag; int H, logH, slot, p;
    if (x < 256)      { in = yg;   mag = mag_yg;   H = 256; logH = 8; slot = 0; p = x * 256 + threadIdx.x; }
    else if (x < 512) { in = mri;  mag = mag_mri;  H = 256; logH = 8; slot = 2; p = (x - 256) * 256 + threadIdx.x; }
    else if (x < 576) { in = py;   mag = mag_py;   H = 128; logH = 7; slot = 4; p = (x - 512) * 256 + threadIdx.x; }
    else              { in = pmri; mag = mag_pmri; H = 128; logH = 7; slot = 6; p = (x - 576) * 256 + threadIdx.x; }
    int HH = H * H;
    const float* ip = in + b * HH;
    int i = p >> logH, j = p & (H - 1);
    auto at = [&](int ii, int jj) -> float {
        return (ii >= 0 && ii < H && jj >= 0 && jj < H) ? ip[(ii << logH) + jj] : 0.0f;
    };
    float a00 = at(i - 1, j - 1), a01 = at(i - 1, j), a02 = at(i - 1, j + 1);
    float a10 = at(i, j - 1),                         a12 = at(i, j + 1);
    float a20 = at(i + 1, j - 1), a21 = at(i + 1, j), a22 = at(i + 1, j + 1);
    float gx = a00 - a02 + 2.0f * a10 - 2.0f * a12 + a20 - a22;
    float gy = a00 + 2.0f * a01 + a02 - a20 - 2.0f * a21 - a22;
    float m = sqrtf(gx * gx + gy * gy + 1e-6f);
    mag[b * HH + p] = m;
    float bm = blockMax(m, threadIdx.x);
    if (threadIdx.x == 0) atomicMax(mx + slot + b, __float_as_uint(bm));
}

// ---------------- 2 charbonnier passes fused ----------------
__global__ __launch_bounds__(256) void egf_charb2(const float* __restrict__ mag_yg,
                                                  const float* __restrict__ mag_mri,
                                                  const float* __restrict__ mag_py,
                                                  const float* __restrict__ mag_pmri,
                                                  const unsigned* __restrict__ mx,
                                                  const float* __restrict__ ehat,
                                                  float* __restrict__ acc) {
    int b = blockIdx.y;
    int x = blockIdx.x;
    const float *magA, *magB; const unsigned *mxA, *mxB;
    float *accC; const float* eh; int HH, p;
    if (x < 256) { magA = mag_yg; magB = mag_mri; mxA = mx + 0; mxB = mx + 2;
                   accC = acc + A_CH1; eh = ehat; HH = 65536; p = x * 256 + threadIdx.x; }
    else         { magA = mag_py; magB = mag_pmri; mxA = mx + 4; mxB = mx + 6;
                   accC = acc + A_CH2; eh = nullptr; HH = 16384; p = (x - 256) * 256 + threadIdx.x; }
    float c = 0.0f, au = 0.0f;
    float da = fmaxf(__uint_as_float(mxA[b]), 1e-6f);
    float db = fmaxf(__uint_as_float(mxB[b]), 1e-6f);
    if (p < HH) {
        float sa = magA[b * HH + p] / da;
        float sb = magB[b * HH + p] / db;
        float d = sa - sb;
        c = sqrtf(d * d + 1e-6f);
        if (eh) au = fabsf(eh[b * HH + p] - sb);
    }
    float tc = blockSum(c, threadIdx.x);
    if (threadIdx.x == 0) atomicAdd(accC, tc);
    if (eh) {
        float ta = blockSum(au, threadIdx.x);
        if (threadIdx.x == 0) atomicAdd(&acc[A_AUX], ta);
    }
}

// ------- SSIM, SEPARABLE, 4 TILES PER BLOCK (dispatch-rate fix) -------------
// grid (8,8,14): each block computes a 2x2 group of 16x16 output tiles
// sequentially, reusing LDS. Barrier alignment: the horizontal phase reads
// only va..ve (not sx/sy); the next tile's vertical write to va..ve is
// separated from this tile's horizontal reads by the post-load __syncthreads.
__global__ __launch_bounds__(256) void egf_ssim3(const float* __restrict__ y,
                                                 const float* __restrict__ ygray,
                                                 const float* __restrict__ mri,
                                                 const float* __restrict__ pet,
                                                 const float* __restrict__ mask,
                                                 float* __restrict__ acc) {
    int z = blockIdx.z;
    const float *xp, *yp, *mp = nullptr; float* accB; int b;
    if (z < 2) {
        b = z; xp = ygray + b * 65536; yp = mri + b * 65536; accB = acc + A_SSIMA;
    } else if (z < 8) {
        int bc = z - 2; b = bc / 3; int c = bc - b * 3;
        xp = y + (b * 3 + c) * 65536; yp = pet + (b * 3 + c) * 65536; accB = acc + A_SSIMB;
    } else {
        int bc = z - 8; b = bc / 3; int c = bc - b * 3;
        xp = y + (b * 3 + c) * 65536; yp = mri + b * 65536; mp = mask + b * 65536; accB = acc + A_SSIMC;
    }
    __shared__ float sx[26][27];
    __shared__ float sy[26][27];
    __shared__ float va[16][27];   // vert-filtered x
    __shared__ float vb[16][27];   // vert-filtered y
    __shared__ float vc[16][27];   // vert-filtered x*x
    __shared__ float vd[16][27];   // vert-filtered y*y
    __shared__ float ve[16][27];   // vert-filtered x*y
    int tid = threadIdx.y * 16 + threadIdx.x;
    float w[11];
    {
        float s = 0.0f;
#pragma unroll
        for (int i = 0; i < 11; i++) { float d = (float)(i - 5); w[i] = expf(-d * d * (1.0f / 4.5f)); s += w[i]; }
        float inv = 1.0f / s;
#pragma unroll
        for (int i = 0; i < 11; i++) w[i] *= inv;
    }
    float vsum = 0.0f;
    for (int st = 0; st < 4; ++st) {
        int ti = (blockIdx.x * 2 + (st >> 1)) * 16;
        int tj = (blockIdx.y * 2 + (st & 1)) * 16;
        for (int t = tid; t < 26 * 26; t += 256) {
            int li = t / 26, lj = t - li * 26;
            int gi = ti + li, gj = tj + lj;
            float a = 0.0f, bb = 0.0f;
            if (gi < 256 && gj < 256) {
                int p = (gi << 8) + gj;
                float m = mp ? mp[p] : 1.0f;
                a = xp[p] * m; bb = yp[p] * m;
            }
            sx[li][lj] = a; sy[li][lj] = bb;
        }
        __syncthreads();
        // vertical pass: 16 output rows x 26 cols
        for (int t = tid; t < 16 * 26; t += 256) {
            int r = t / 26, c = t - r * 26;
            float s0 = 0, s1 = 0, s2 = 0, s3 = 0, s4 = 0;
#pragma unroll
            for (int k = 0; k < 11; k++) {
                float wk = w[k];
                float a = sx[r + k][c], bb = sy[r + k][c];
                s0 += wk * a; s1 += wk * bb;
                s2 += wk * a * a; s3 += wk * bb * bb; s4 += wk * a * bb;
            }
            va[r][c] = s0; vb[r][c] = s1; vc[r][c] = s2; vd[r][c] = s3; ve[r][c] = s4;
        }
        __syncthreads();
        // horizontal pass: one output per thread
        int oi = ti + threadIdx.y, oj = tj + threadIdx.x;
        if (oi < 246 && oj < 246) {
            float mu1 = 0, mu2 = 0, xx = 0, yy = 0, xy = 0;
            int ty = threadIdx.y, tx = threadIdx.x;
#pragma unroll
            for (int k = 0; k < 11; k++) {
                float wk = w[k];
                mu1 += wk * va[ty][tx + k]; mu2 += wk * vb[ty][tx + k];
                xx  += wk * vc[ty][tx + k]; yy  += wk * vd[ty][tx + k];
                xy  += wk * ve[ty][tx + k];
            }
            float s11 = xx - mu1 * mu1, s22 = yy - mu2 * mu2, s12 = xy - mu1 * mu2;
            const float C1 = 1e-4f, C2 = 9e-4f;
            vsum += ((2.0f * mu1 * mu2 + C1) * (2.0f * s12 + C2)) /
                    ((mu1 * mu1 + mu2 * mu2 + C1) * (s11 + s22 + C2));
        }
        __syncthreads();   // sx/sy reuse vs this tile's vertical reads; cheap
    }
    float tot = blockSum(vsum, tid);
    if (tid == 0) atomicAdd(&accB[b], tot);
}

// ------ gaussian smooth, one-pass LDS-tiled, 4 TILES PER BLOCK --------------
__device__ __forceinline__ int refl256(int i) { return i < 0 ? -1 - i : (i > 255 ? 511 - i : i); }

__device__ __forceinline__ void gauss9(float* w) {
    float s = 0.0f;
#pragma unroll
    for (int t = 0; t < 9; t++) { float d = (float)(t - 4); w[t] = expf(-0.5f * d * d); s += w[t]; }
    float inv = 1.0f / s;
#pragma unroll
    for (int t = 0; t < 9; t++) w[t] *= inv;
}

// grid (8,8,6): each block does a 2x2 group of 16x16 tiles sequentially.
// NOTE: final phase reads sx, so each tile starts with a __syncthreads to
// order the previous tile's reads before this tile's loads overwrite sx.
__global__ __launch_bounds__(256) void egf_smooth1(const float* __restrict__ y,
                                                   float* __restrict__ acc) {
    int bc = blockIdx.z;
    const float* ip = y + bc * 65536;
    __shared__ float sx[24][25];
    __shared__ float sv[16][25];
    int tid = threadIdx.x;
    float w[9]; gauss9(w);
    float dsum = 0.0f;
    for (int st = 0; st < 4; ++st) {
        int i0 = (blockIdx.x * 2 + (st >> 1)) * 16;
        int j0 = (blockIdx.y * 2 + (st & 1)) * 16;
        __syncthreads();   // prev tile's sx/sv reads complete before overwrite
        for (int t = tid; t < 576; t += 256) {
            int li = t / 24, lj = t - li * 24;
            int gi = refl256(i0 + li - 4), gj = refl256(j0 + lj - 4);
            sx[li][lj] = ip[(gi << 8) + gj];
        }
        __syncthreads();
        for (int t = tid; t < 384; t += 256) {
            int li = t / 24, lj = t - li * 24;     // li in [0,16), lj in [0,24)
            float s = 0.0f;
#pragma unroll
            for (int k = 0; k < 9; k++) s += w[k] * sx[li + k][lj];
            sv[li][lj] = s;
        }
        __syncthreads();
        int ty = tid >> 4, tx = tid & 15;
        float s = 0.0f;
#pragma unroll
        for (int k = 0; k < 9; k++) s += w[k] * sv[ty][tx + k];
        float d = s - sx[ty + 4][tx + 4];
        dsum += d * d;
    }
    float tt = blockSum(dsum, tid);
    if (tid == 0) atomicAdd(acc, tt);
}

// ------ fused combine (staging) helper, NCH=64, SINGLE-FLOAT lse partials ---
// partial[chunk][col] = log2( sum_r exp2(e_r - b_c) )  (per 64-row chunk).
// Combine: M = max_k lse_k; S = sum_k exp2(lse_k - M)  — exact LSE merge.
__device__ __forceinline__ float stageCombine(const float* __restrict__ Pin,
                                              int qbase, int row, int h, int r_local,
                                              float* sm, float* ss, int tid) {
    const float* p = Pin + qbase + (h * 16) * NPTS + row;
    float t[16];
#pragma unroll
    for (int k = 0; k < 16; k++) t[k] = p[k * NPTS];
    float m16 = -3.4e38f;
#pragma unroll
    for (int k = 0; k < 16; k++) m16 = fmaxf(m16, t[k]);
    float s16 = 0.0f;
#pragma unroll
    for (int k = 0; k < 16; k++) s16 += __builtin_amdgcn_exp2f(t[k] - m16);
    sm[h * 64 + r_local] = m16;
    ss[h * 64 + r_local] = s16;
    __syncthreads();
    float v = 0.0f;
    if (tid < 64) {
        float m0 = sm[tid], m1 = sm[64 + tid], m2 = sm[128 + tid], m3 = sm[192 + tid];
        float M = fmaxf(fmaxf(m0, m1), fmaxf(m2, m3));
        float S = ss[tid]       * __builtin_amdgcn_exp2f(m0 - M) +
                  ss[64 + tid]  * __builtin_amdgcn_exp2f(m1 - M) +
                  ss[128 + tid] * __builtin_amdgcn_exp2f(m2 - M) +
                  ss[192 + tid] * __builtin_amdgcn_exp2f(m3 - M);
        v = EPS_LOGN - EPS_LN2 * (M + log2f(S));
    }
    return v;
}

// ---------------- sinkhorn half: two-pass (VERIFIED core), CHUNK=64 ---------
// lse single-float partial format (verified round 8).
__global__ __launch_bounds__(256) void egf_sink_half8(const float4* __restrict__ pts,
                                                      const float* __restrict__ Pin,
                                                      float* __restrict__ Pout,
                                                      int dir, int init) {
    int q = blockIdx.z; int b = q / 3, t = q - b * 3;
    int xsel = (t == 2) ? 1 : 0;
    int ysel = (t == 1) ? 0 : 1;
    const float4* rowP = pts + (b * 2 + (dir ? ysel : xsel)) * NPTS;
    const float4* colP = pts + (b * 2 + (dir ? xsel : ysel)) * NPTS;

    __shared__ float4 srow[CHUNK];
    __shared__ float sm[256], ss[256];
    int tid = threadIdx.x;
    int chunk = blockIdx.y;
    int r_local = tid & 63, h = tid >> 6;
    int row = chunk * CHUNK + r_local;

    // prefetch column fragments (independent of the staging barrier)
    int col0 = blockIdx.x * COLS_PER_BLK + tid;
    float4 cf[8];
#pragma unroll
    for (int k = 0; k < 8; k++) cf[k] = colP[col0 + k * 256];

    float v = 0.0f;
    if (!init)
        v = stageCombine(Pin, q * QSTRIDE, row, h, r_local, sm, ss, tid);
    if (tid < 64) {
        float4 pp = rowP[row];
        srow[tid] = make_float4(pp.x * INV_EPS_L2E, pp.y * INV_EPS_L2E,
                                pp.z * INV_EPS_L2E, (v - pp.w) * INV_EPS_L2E);
    }
    __syncthreads();

    v2f cx[4], cy[4], cz[4], cw[4];
#pragma unroll
    for (int p = 0; p < 4; p++) {
        cx[p] = (v2f){cf[2 * p].x, cf[2 * p + 1].x};
        cy[p] = (v2f){cf[2 * p].y, cf[2 * p + 1].y};
        cz[p] = (v2f){cf[2 * p].z, cf[2 * p + 1].z};
        cw[p] = (v2f){cf[2 * p].w * INV_EPS_L2E, cf[2 * p + 1].w * INV_EPS_L2E};
    }
    v2f mx[4];
#pragma unroll
    for (int p = 0; p < 4; p++) mx[p] = (v2f){-3.4e38f, -3.4e38f};
#pragma unroll 4
    for (int rr = 0; rr < CHUNK; rr++) {
        float4 rp = srow[rr];
        v2f rxy = (v2f){rp.x, rp.y};
        v2f rzw = (v2f){rp.z, rp.w};
#pragma unroll
        for (int p = 0; p < 4; p++) {
            v2f e = pk_fma_blo_chi(rzw, cz[p], rzw);   // Z*cz + W
            e = pk_fma_bhi(rxy, cy[p], e);             // + Y*cy
            e = pk_fma_blo(rxy, cx[p], e);             // + X*cx
            mx[p].x = fmaxf(mx[p].x, e.x);
            mx[p].y = fmaxf(mx[p].y, e.y);
        }
    }
    v2f mneg[4], sa[4];
#pragma unroll
    for (int p = 0; p < 4; p++) { mneg[p] = -mx[p]; sa[p] = (v2f){0.0f, 0.0f}; }
#pragma unroll 4
    for (int rr = 0; rr < CHUNK; rr++) {
        float4 rp = srow[rr];
        v2f rxy = (v2f){rp.x, rp.y};
        v2f rzw = (v2f){rp.z, rp.w};
#pragma unroll
        for (int p = 0; p < 4; p++) {
            v2f e = pk_fma_blo(rzw, cz[p], mneg[p]);   // Z*cz - mx
            e = pk_fma_bhi(rxy, cy[p], e);             // + Y*cy
            e = pk_fma_blo(rxy, cx[p], e);             // + X*cx
            e = pk_add_bhi(e, rzw);                    // + W
            v2f ex;
            ex.x = __builtin_amdgcn_exp2f(e.x);
            ex.y = __builtin_amdgcn_exp2f(e.y);
            sa[p] = pk_add(sa[p], ex);
        }
    }
    float* om = Pout + q * QSTRIDE + chunk * NPTS;
#pragma unroll
    for (int p = 0; p < 4; p++) {
        om[col0 + (2 * p) * 256]     = mx[p].x - cw[p].x + log2f(sa[p].x);
        om[col0 + (2 * p + 1) * 256] = mx[p].y - cw[p].y + log2f(sa[p].y);
    }
}

// ---------------- final scalar assembly (device helper) ----------------
__device__ __forceinline__ void finalize_body(float* acc, float* out) {
    auto rd = [&](int i) -> float { return atomicAdd(&acc[i], 0.0f); };
    const float AREA = 246.0f * 246.0f;
    float ssim_m = 1.0f - (rd(A_SSIMA) + rd(A_SSIMA + 1)) / (2.0f * AREA);
    float ssim_p = 1.0f - (rd(A_SSIMB) + rd(A_SSIMB + 1)) / (2.0f * 3.0f * AREA);
    float g_cons = rd(A_CH1) / (2.0f * 65536.0f) + rd(A_CH2) / (2.0f * 16384.0f);
    float aux = rd(A_AUX) / (2.0f * 65536.0f);
    float inc0 = (rd(A_CNT)     >= 31.5f) ? 1.0f : 0.0f;
    float inc1 = (rd(A_CNT + 1) >= 31.5f) ? 1.0f : 0.0f;
    float v0 = rd(A_SINK + 0), v1 = rd(A_SINK + 1), v2 = rd(A_SINK + 2);
    float v3 = rd(A_SINK + 3), v4 = rd(A_SINK + 4), v5 = rd(A_SINK + 5);
    float Lt = (inc0 * (v0 - 0.5f * v1 - 0.5f * v2) +
                inc1 * (v3 - 0.5f * v4 - 0.5f * v5)) * 0.5f;
    float Lo = (inc0 * rd(A_LOUT) + inc1 * rd(A_LOUT + 1)) / (3.0f * 65536.0f) * 0.5f;
    float Ls = (inc0 * (1.0f - rd(A_SSIMC) / (3.0f * AREA)) +
                inc1 * (1.0f - rd(A_SSIMC + 1) / (3.0f * AREA))) * 0.5f;
    float Li = 2.5f * rd(A_INT) / (2.0f * 3.0f * 65536.0f);
    float Lsm = rd(A_SMOOTH) / (2.0f * 3.0f * 65536.0f);
    float total = 0.8f * Lt + 0.3f * Lo + 0.5f * Ls + Li + 0.2f * Lsm;
    out[0] = total; out[1] = ssim_m; out[2] = ssim_p; out[3] = g_cons; out[4] = aux;
}

// ---------------- sinkhorn value + last-block finalize ----------------
// grid (128, 6): blockIdx.x>>6 selects f/g partials, &63 selects the 64-row chunk.
__global__ __launch_bounds__(256) void egf_sink_val8(const float* __restrict__ Pf,
                                                     const float* __restrict__ Pg,
                                                     float* __restrict__ acc,
                                                     float* __restrict__ out) {
    int q = blockIdx.y;
    int side = blockIdx.x >> 6;
    int chunk = blockIdx.x & 63;
    const float* P = side ? Pg : Pf;
    __shared__ float sm[256], ss[256];
    int tid = threadIdx.x;
    int r_local = tid & 63, h = tid >> 6;
    int row = chunk * CHUNK + r_local;
    float v = stageCombine(P, q * QSTRIDE, row, h, r_local, sm, ss, tid);
    float tot = blockSum(v, tid);
    if (tid == 0) {
        atomicAdd(&acc[A_SINK + q], tot * (1.0f / 4096.0f));
        __threadfence();
        unsigned old = atomicAdd((unsigned*)&acc[A_DONE], 1u);
        if (old == 128u * 6u - 1u) finalize_body(acc, out);   // last block finalizes
    }
}

// ---------------- host launch ----------------
extern "C" void kernel_launch(void* const* d_in, const int* in_sizes, int n_in,
                              void* d_out, int out_size, void* d_ws, size_t ws_size,
                              hipStream_t stream) {
    const float* y    = (const float*)d_in[0];
    const float* mri  = (const float*)d_in[1];
    const float* pet  = (const float*)d_in[2];
    const float* mask = (const float*)d_in[3];
    const float* ehat = (const float*)d_in[4];
    const int*   idx  = (const int*)d_in[5];
    float* out = (float*)d_out;
    float* ws  = (float*)d_ws;

    float* acc   = ws;                    // 64 floats
    float4* pts  = (float4*)(ws + 64);    // 4*4096 float4 = 65536 floats
    float* base  = ws + 64 + 65536;

    // sinkhorn partials: 2 float planes of 6*64*4096 elements (6.3 MB apiece)
    float* Pf = base;
    float* Pg = Pf + QSTRIDE * 6;
    float* ibase = base + 2 * QSTRIDE * 6;

    // image scratch
    float* ygray    = ibase;              // 131072
    float* py       = ygray + 131072;     // 32768
    float* pmri     = py + 32768;         // 32768
    float* mag_yg   = pmri + 32768;       // 131072
    float* mag_mri  = mag_yg + 131072;    // 131072
    float* mag_py   = mag_mri + 131072;   // 32768
    float* mag_pmri = mag_py + 32768;     // 32768

    hipMemsetAsync(acc, 0, 64 * sizeof(float), stream);

    unsigned* mx = (unsigned*)(acc + A_MAX);

    egf_prep_pool<<<dim3(336, 2), 256, 0, stream>>>(y, pet, mri, mask, idx,
                                                    ygray, py, pmri, pts, acc);
    egf_sobel4<<<dim3(640, 2), 256, 0, stream>>>(ygray, mri, py, pmri,
                                                 mag_yg, mag_mri, mag_py, mag_pmri, mx);
    egf_charb2<<<dim3(320, 2), 256, 0, stream>>>(mag_yg, mag_mri, mag_py, mag_pmri, mx, ehat, acc);
    egf_ssim3<<<dim3(8, 8, 14), dim3(16, 16), 0, stream>>>(y, ygray, mri, pet, mask, acc);
    egf_smooth1<<<dim3(8, 8, 6), 256, 0, stream>>>(y, acc + A_SMOOTH);

    dim3 sgrid(NCB, NCH, 6);   // 2 x 64 x 6 = 768 blocks
    for (int it = 0; it < 11; ++it) {
        egf_sink_half8<<<sgrid, 256, 0, stream>>>(pts, Pf, Pg, 0, it == 0 ? 1 : 0);
        egf_sink_half8<<<sgrid, 256, 0, stream>>>(pts, Pg, Pf, 1, 0);
    }
    egf_sink_val8<<<dim3(128, 6), 256, 0, stream>>>(Pf, Pg, acc, out);
}

// Round 10
// 717.053 us; speedup vs baseline: 1.1769x; 1.0414x over previous
//
#include <hip/hip_runtime.h>
#include <math.h>

// ---------------- constants ----------------
#define INV_EPS_L2E 577.0780163555854f   // (1/eps) * log2(e) = 1/(eps*ln2)
#define EPS_LOGN 0.02079441542f          // eps * ln(4096) = -eps*loga
#define EPS_LN2 0.00173286795f           // eps * ln(2)

#define NPTS 4096
#define CHUNK 64
#define NCH 64            // 4096/64
#define CPT 8             // columns per thread (4 packed pairs)
#define COLS_PER_BLK 2048 // 256*CPT
#define NCB 2             // 4096/2048
#define QSTRIDE (NCH * NPTS)  // float elements per problem in partial arrays (lse format)

typedef float v2f __attribute__((ext_vector_type(2)));

// True packed-fp32 ops with VOP3P op_sel broadcasts. gfx950 packed-f32 set is
// ONLY {v_pk_fma_f32, v_pk_mul_f32, v_pk_add_f32} — no v_pk_max_f32.
__device__ __forceinline__ v2f pk_add(v2f a, v2f b) {
    v2f d;
    asm("v_pk_add_f32 %0, %1, %2" : "=v"(d) : "v"(a), "v"(b));
    return d;
}
// lo(a) broadcast to both lanes; b,c normal
__device__ __forceinline__ v2f pk_fma_blo(v2f a, v2f b, v2f c) {
    v2f d;
    asm("v_pk_fma_f32 %0, %1, %2, %3 op_sel:[0,0,0] op_sel_hi:[0,1,1]"
        : "=v"(d) : "v"(a), "v"(b), "v"(c));
    return d;
}
// hi(a) broadcast; b,c normal
__device__ __forceinline__ v2f pk_fma_bhi(v2f a, v2f b, v2f c) {
    v2f d;
    asm("v_pk_fma_f32 %0, %1, %2, %3 op_sel:[1,0,0] op_sel_hi:[1,1,1]"
        : "=v"(d) : "v"(a), "v"(b), "v"(c));
    return d;
}
// lo(a) broadcast AND hi(c) broadcast; b normal   (a.lo*b + c.hi per lane)
__device__ __forceinline__ v2f pk_fma_blo_chi(v2f a, v2f b, v2f c) {
    v2f d;
    asm("v_pk_fma_f32 %0, %1, %2, %3 op_sel:[0,0,1] op_sel_hi:[0,1,1]"
        : "=v"(d) : "v"(a), "v"(b), "v"(c));
    return d;
}
// a + hi(b) broadcast
__device__ __forceinline__ v2f pk_add_bhi(v2f a, v2f b) {
    v2f d;
    asm("v_pk_add_f32 %0, %1, %2 op_sel:[0,1] op_sel_hi:[1,1]"
        : "=v"(d) : "v"(a), "v"(b));
    return d;
}

// accumulator slots (floats) at start of workspace
constexpr int A_SSIMA  = 0;   // [B]
constexpr int A_SSIMB  = 2;   // [B]
constexpr int A_SSIMC  = 4;   // [B]
constexpr int A_CH1    = 6;
constexpr int A_CH2    = 7;
constexpr int A_AUX    = 8;
constexpr int A_INT    = 9;
constexpr int A_LOUT   = 10;  // [B]
constexpr int A_CNT    = 12;  // [B]
constexpr int A_SMOOTH = 14;
constexpr int A_SINK   = 16;  // [6]
constexpr int A_MAX    = 32;  // 8 uint slots (4 fields x B), float-bits
constexpr int A_DONE   = 40;  // uint: last-block-done counter for val+finalize

// ---------------- block reduction helpers (blockDim == 256) ----------------
__device__ __forceinline__ float blockSum(float v, int tid) {
#pragma unroll
    for (int o = 32; o; o >>= 1) v += __shfl_down(v, o, 64);
    __shared__ float sh[4];
    __syncthreads();
    if ((tid & 63) == 0) sh[tid >> 6] = v;
    __syncthreads();
    return sh[0] + sh[1] + sh[2] + sh[3];
}

__device__ __forceinline__ float blockMax(float v, int tid) {
#pragma unroll
    for (int o = 32; o; o >>= 1) v = fmaxf(v, __shfl_down(v, o, 64));
    __shared__ float sh[4];
    __syncthreads();
    if ((tid & 63) == 0) sh[tid >> 6] = v;
    __syncthreads();
    return fmaxf(fmaxf(sh[0], sh[1]), fmaxf(sh[2], sh[3]));
}

// -- fused prep + avgpool2 + gather, 4 items/thread (block-merge transform) --
// grid (84, 2): x<64 prep (64x1024), x<80 pool (16x1024), x<84 gather (4x1024)
__global__ __launch_bounds__(256) void egf_prep_pool(const float* __restrict__ y,
                                                     const float* __restrict__ pet,
                                                     const float* __restrict__ mri,
                                                     const float* __restrict__ mask,
                                                     const int* __restrict__ idx,
                                                     float* __restrict__ ygray,
                                                     float* __restrict__ py,
                                                     float* __restrict__ pmri,
                                                     float4* __restrict__ pts,
                                                     float* __restrict__ acc) {
    int b = blockIdx.y;
    int x = blockIdx.x;
    if (x < 64) {
        float inten = 0.0f, lout = 0.0f, cnt = 0.0f;
#pragma unroll
        for (int k = 0; k < 4; k++) {
            int p = x * 1024 + k * 256 + threadIdx.x;    // 64*1024 = 65536
            float m  = mask[b * 65536 + p];
            float y0 = y[(b * 3 + 0) * 65536 + p];
            float y1 = y[(b * 3 + 1) * 65536 + p];
            float y2 = y[(b * 3 + 2) * 65536 + p];
            float q0 = pet[(b * 3 + 0) * 65536 + p];
            float q1 = pet[(b * 3 + 1) * 65536 + p];
            float q2 = pet[(b * 3 + 2) * 65536 + p];
            ygray[b * 65536 + p] = (y0 + y1 + y2) * (1.0f / 3.0f);
            float d0 = m * y0 - m * q0, d1 = m * y1 - m * q1, d2 = m * y2 - m * q2;
            inten += d0 * d0 + d1 * d1 + d2 * d2;
            float im = 1.0f - m;
            float o0 = y0 * im, o1 = y1 * im, o2 = y2 * im;
            lout += o0 * o0 + o1 * o1 + o2 * o2;
            cnt += (m > 0.1f) ? 1.0f : 0.0f;
        }
        float t;
        t = blockSum(inten, threadIdx.x); if (threadIdx.x == 0) atomicAdd(&acc[A_INT], t);
        t = blockSum(lout,  threadIdx.x); if (threadIdx.x == 0) atomicAdd(&acc[A_LOUT + b], t);
        t = blockSum(cnt,   threadIdx.x); if (threadIdx.x == 0) atomicAdd(&acc[A_CNT + b], t);
    } else if (x < 80) {
#pragma unroll
        for (int k = 0; k < 4; k++) {
            int po = (x - 64) * 1024 + k * 256 + threadIdx.x;   // 16*1024 = 16384
            int i = po >> 7, j = po & 127;
            int p0 = (i * 2) * 256 + j * 2;
            float s = 0.0f;
#pragma unroll
            for (int c = 0; c < 3; c++) {
                const float* ip = y + (b * 3 + c) * 65536;
                s += ip[p0] + ip[p0 + 1] + ip[p0 + 256] + ip[p0 + 257];
            }
            py[b * 16384 + po] = s * (1.0f / 12.0f);
            const float* mp = mri + b * 65536;
            pmri[b * 16384 + po] = (mp[p0] + mp[p0 + 1] + mp[p0 + 256] + mp[p0 + 257]) * 0.25f;
        }
    } else {
        // gather masked point clouds: 2y * 4x * 1024 = 8192 items
#pragma unroll
        for (int k = 0; k < 4; k++) {
            int t = (b * 4 + (x - 80)) * 1024 + k * 256 + threadIdx.x;   // < 8192
            int bb = t >> 12, j = t & 4095;
            int p = idx[bb * 4096 + j];
            float m = mask[bb * 65536 + p];
            float a0 = y[(bb * 3 + 0) * 65536 + p] * m;
            float a1 = y[(bb * 3 + 1) * 65536 + p] * m;
            float a2 = y[(bb * 3 + 2) * 65536 + p] * m;
            pts[(bb * 2 + 0) * 4096 + j] = make_float4(a0, a1, a2, 0.5f * (a0 * a0 + a1 * a1 + a2 * a2));
            float c0 = pet[(bb * 3 + 0) * 65536 + p] * m;
            float c1 = pet[(bb * 3 + 1) * 65536 + p] * m;
            float c2 = pet[(bb * 3 + 2) * 65536 + p] * m;
            pts[(bb * 2 + 1) * 4096 + j] = make_float4(c0, c1, c2, 0.5f * (c0 * c0 + c1 * c1 + c2 * c2));
        }
    }
}

// ------- 4 sobel passes fused, 4 px/thread (block-merge transform) ----------
// grid (160, 2): x<64 yg, x<128 mri (64 blocks x 1024 px), x<144 py,
// x<160 pmri (16 blocks x 1024 px).
__global__ __launch_bounds__(256) void egf_sobel4(const float* __restrict__ yg,
                                                  const float* __restrict__ mri,
                                                  const float* __restrict__ py,
                                                  const float* __restrict__ pmri,
                                                  float* __restrict__ mag_yg,
                                                  float* __restrict__ mag_mri,
                                                  float* __restrict__ mag_py,
                                                  float* __restrict__ mag_pmri,
                                                  unsigned* __restrict__ mx) {
    int b = blockIdx.y;
    int x = blockIdx.x;
    const float* in; float* mag; int H, logH, slot, p0;
    if (x < 64)       { in = yg;   mag = mag_yg;   H = 256; logH = 8; slot = 0; p0 = x * 1024; }
    else if (x < 128) { in = mri;  mag = mag_mri;  H = 256; logH = 8; slot = 2; p0 = (x - 64) * 1024; }
    else if (x < 144) { in = py;   mag = mag_py;   H = 128; logH = 7; slot = 4; p0 = (x - 128) * 1024; }
    else              { in = pmri; mag = mag_pmri; H = 128; logH = 7; slot = 6; p0 = (x - 144) * 1024; }
    int HH = H * H;
    const float* ip = in + b * HH;
    float bm = 0.0f;
#pragma unroll
    for (int k = 0; k < 4; k++) {
        int p = p0 + k * 256 + threadIdx.x;
        int i = p >> logH, j = p & (H - 1);
        auto at = [&](int ii, int jj) -> float {
            return (ii >= 0 && ii < H && jj >= 0 && jj < H) ? ip[(ii << logH) + jj] : 0.0f;
        };
        float a00 = at(i - 1, j - 1), a01 = at(i - 1, j), a02 = at(i - 1, j + 1);
        float a10 = at(i, j - 1),                         a12 = at(i, j + 1);
        float a20 = at(i + 1, j - 1), a21 = at(i + 1, j), a22 = at(i + 1, j + 1);
        float gx = a00 - a02 + 2.0f * a10 - 2.0f * a12 + a20 - a22;
        float gy = a00 + 2.0f * a01 + a02 - a20 - 2.0f * a21 - a22;
        float m = sqrtf(gx * gx + gy * gy + 1e-6f);
        mag[b * HH + p] = m;
        bm = fmaxf(bm, m);
    }
    float bmax = blockMax(bm, threadIdx.x);
    if (threadIdx.x == 0) atomicMax(mx + slot + b, __float_as_uint(bmax));
}

// ------- 2 charbonnier passes fused, 4 px/thread ----------------------------
// grid (80, 2): x<64 big pair (64x1024), x<80 small pair (16x1024)
__global__ __launch_bounds__(256) void egf_charb2(const float* __restrict__ mag_yg,
                                                  const float* __restrict__ mag_mri,
                                                  const float* __restrict__ mag_py,
                                                  const float* __restrict__ mag_pmri,
                                                  const unsigned* __restrict__ mx,
                                                  const float* __restrict__ ehat,
                                                  float* __restrict__ acc) {
    int b = blockIdx.y;
    int x = blockIdx.x;
    const float *magA, *magB; const unsigned *mxA, *mxB;
    float *accC; const float* eh; int HH, p0;
    if (x < 64) { magA = mag_yg; magB = mag_mri; mxA = mx + 0; mxB = mx + 2;
                  accC = acc + A_CH1; eh = ehat; HH = 65536; p0 = x * 1024; }
    else        { magA = mag_py; magB = mag_pmri; mxA = mx + 4; mxB = mx + 6;
                  accC = acc + A_CH2; eh = nullptr; HH = 16384; p0 = (x - 64) * 1024; }
    float da = fmaxf(__uint_as_float(mxA[b]), 1e-6f);
    float db = fmaxf(__uint_as_float(mxB[b]), 1e-6f);
    float ida = 1.0f / da, idb = 1.0f / db;
    float c = 0.0f, au = 0.0f;
#pragma unroll
    for (int k = 0; k < 4; k++) {
        int p = p0 + k * 256 + threadIdx.x;
        float sa = magA[b * HH + p] * ida;
        float sb = magB[b * HH + p] * idb;
        float d = sa - sb;
        c += sqrtf(d * d + 1e-6f);
        if (eh) au += fabsf(eh[b * HH + p] - sb);
    }
    float tc = blockSum(c, threadIdx.x);
    if (threadIdx.x == 0) atomicAdd(accC, tc);
    if (eh) {
        float ta = blockSum(au, threadIdx.x);
        if (threadIdx.x == 0) atomicAdd(&acc[A_AUX], ta);
    }
}

// ------- SSIM, SEPARABLE, 4 TILES PER BLOCK (verified round 9) --------------
__global__ __launch_bounds__(256) void egf_ssim3(const float* __restrict__ y,
                                                 const float* __restrict__ ygray,
                                                 const float* __restrict__ mri,
                                                 const float* __restrict__ pet,
                                                 const float* __restrict__ mask,
                                                 float* __restrict__ acc) {
    int z = blockIdx.z;
    const float *xp, *yp, *mp = nullptr; float* accB; int b;
    if (z < 2) {
        b = z; xp = ygray + b * 65536; yp = mri + b * 65536; accB = acc + A_SSIMA;
    } else if (z < 8) {
        int bc = z - 2; b = bc / 3; int c = bc - b * 3;
        xp = y + (b * 3 + c) * 65536; yp = pet + (b * 3 + c) * 65536; accB = acc + A_SSIMB;
    } else {
        int bc = z - 8; b = bc / 3; int c = bc - b * 3;
        xp = y + (b * 3 + c) * 65536; yp = mri + b * 65536; mp = mask + b * 65536; accB = acc + A_SSIMC;
    }
    __shared__ float sx[26][27];
    __shared__ float sy[26][27];
    __shared__ float va[16][27];   // vert-filtered x
    __shared__ float vb[16][27];   // vert-filtered y
    __shared__ float vc[16][27];   // vert-filtered x*x
    __shared__ float vd[16][27];   // vert-filtered y*y
    __shared__ float ve[16][27];   // vert-filtered x*y
    int tid = threadIdx.y * 16 + threadIdx.x;
    float w[11];
    {
        float s = 0.0f;
#pragma unroll
        for (int i = 0; i < 11; i++) { float d = (float)(i - 5); w[i] = expf(-d * d * (1.0f / 4.5f)); s += w[i]; }
        float inv = 1.0f / s;
#pragma unroll
        for (int i = 0; i < 11; i++) w[i] *= inv;
    }
    float vsum = 0.0f;
    for (int st = 0; st < 4; ++st) {
        int ti = (blockIdx.x * 2 + (st >> 1)) * 16;
        int tj = (blockIdx.y * 2 + (st & 1)) * 16;
        for (int t = tid; t < 26 * 26; t += 256) {
            int li = t / 26, lj = t - li * 26;
            int gi = ti + li, gj = tj + lj;
            float a = 0.0f, bb = 0.0f;
            if (gi < 256 && gj < 256) {
                int p = (gi << 8) + gj;
                float m = mp ? mp[p] : 1.0f;
                a = xp[p] * m; bb = yp[p] * m;
            }
            sx[li][lj] = a; sy[li][lj] = bb;
        }
        __syncthreads();
        // vertical pass: 16 output rows x 26 cols
        for (int t = tid; t < 16 * 26; t += 256) {
            int r = t / 26, c = t - r * 26;
            float s0 = 0, s1 = 0, s2 = 0, s3 = 0, s4 = 0;
#pragma unroll
            for (int k = 0; k < 11; k++) {
                float wk = w[k];
                float a = sx[r + k][c], bb = sy[r + k][c];
                s0 += wk * a; s1 += wk * bb;
                s2 += wk * a * a; s3 += wk * bb * bb; s4 += wk * a * bb;
            }
            va[r][c] = s0; vb[r][c] = s1; vc[r][c] = s2; vd[r][c] = s3; ve[r][c] = s4;
        }
        __syncthreads();
        // horizontal pass: one output per thread
        int oi = ti + threadIdx.y, oj = tj + threadIdx.x;
        if (oi < 246 && oj < 246) {
            float mu1 = 0, mu2 = 0, xx = 0, yy = 0, xy = 0;
            int ty = threadIdx.y, tx = threadIdx.x;
#pragma unroll
            for (int k = 0; k < 11; k++) {
                float wk = w[k];
                mu1 += wk * va[ty][tx + k]; mu2 += wk * vb[ty][tx + k];
                xx  += wk * vc[ty][tx + k]; yy  += wk * vd[ty][tx + k];
                xy  += wk * ve[ty][tx + k];
            }
            float s11 = xx - mu1 * mu1, s22 = yy - mu2 * mu2, s12 = xy - mu1 * mu2;
            const float C1 = 1e-4f, C2 = 9e-4f;
            vsum += ((2.0f * mu1 * mu2 + C1) * (2.0f * s12 + C2)) /
                    ((mu1 * mu1 + mu2 * mu2 + C1) * (s11 + s22 + C2));
        }
        __syncthreads();   // sx/sy reuse vs this tile's vertical reads; cheap
    }
    float tot = blockSum(vsum, tid);
    if (tid == 0) atomicAdd(&accB[b], tot);
}

// ------ gaussian smooth, one-pass LDS-tiled, 4 TILES PER BLOCK (verified) ---
__device__ __forceinline__ int refl256(int i) { return i < 0 ? -1 - i : (i > 255 ? 511 - i : i); }

__device__ __forceinline__ void gauss9(float* w) {
    float s = 0.0f;
#pragma unroll
    for (int t = 0; t < 9; t++) { float d = (float)(t - 4); w[t] = expf(-0.5f * d * d); s += w[t]; }
    float inv = 1.0f / s;
#pragma unroll
    for (int t = 0; t < 9; t++) w[t] *= inv;
}

__global__ __launch_bounds__(256) void egf_smooth1(const float* __restrict__ y,
                                                   float* __restrict__ acc) {
    int bc = blockIdx.z;
    const float* ip = y + bc * 65536;
    __shared__ float sx[24][25];
    __shared__ float sv[16][25];
    int tid = threadIdx.x;
    float w[9]; gauss9(w);
    float dsum = 0.0f;
    for (int st = 0; st < 4; ++st) {
        int i0 = (blockIdx.x * 2 + (st >> 1)) * 16;
        int j0 = (blockIdx.y * 2 + (st & 1)) * 16;
        __syncthreads();   // prev tile's sx/sv reads complete before overwrite
        for (int t = tid; t < 576; t += 256) {
            int li = t / 24, lj = t - li * 24;
            int gi = refl256(i0 + li - 4), gj = refl256(j0 + lj - 4);
            sx[li][lj] = ip[(gi << 8) + gj];
        }
        __syncthreads();
        for (int t = tid; t < 384; t += 256) {
            int li = t / 24, lj = t - li * 24;     // li in [0,16), lj in [0,24)
            float s = 0.0f;
#pragma unroll
            for (int k = 0; k < 9; k++) s += w[k] * sx[li + k][lj];
            sv[li][lj] = s;
        }
        __syncthreads();
        int ty = tid >> 4, tx = tid & 15;
        float s = 0.0f;
#pragma unroll
        for (int k = 0; k < 9; k++) s += w[k] * sv[ty][tx + k];
        float d = s - sx[ty + 4][tx + 4];
        dsum += d * d;
    }
    float tt = blockSum(dsum, tid);
    if (tid == 0) atomicAdd(acc, tt);
}

// ------ fused combine (staging) helper, NCH=64, SINGLE-FLOAT lse partials ---
// partial[chunk][col] = log2( sum_r exp2(e_r - b_c) )  (per 64-row chunk).
// Combine: M = max_k lse_k; S = sum_k exp2(lse_k - M)  — exact LSE merge.
__device__ __forceinline__ float stageCombine(const float* __restrict__ Pin,
                                              int qbase, int row, int h, int r_local,
                                              float* sm, float* ss, int tid) {
    const float* p = Pin + qbase + (h * 16) * NPTS + row;
    float t[16];
#pragma unroll
    for (int k = 0; k < 16; k++) t[k] = p[k * NPTS];
    float m16 = -3.4e38f;
#pragma unroll
    for (int k = 0; k < 16; k++) m16 = fmaxf(m16, t[k]);
    float s16 = 0.0f;
#pragma unroll
    for (int k = 0; k < 16; k++) s16 += __builtin_amdgcn_exp2f(t[k] - m16);
    sm[h * 64 + r_local] = m16;
    ss[h * 64 + r_local] = s16;
    __syncthreads();
    float v = 0.0f;
    if (tid < 64) {
        float m0 = sm[tid], m1 = sm[64 + tid], m2 = sm[128 + tid], m3 = sm[192 + tid];
        float M = fmaxf(fmaxf(m0, m1), fmaxf(m2, m3));
        float S = ss[tid]       * __builtin_amdgcn_exp2f(m0 - M) +
                  ss[64 + tid]  * __builtin_amdgcn_exp2f(m1 - M) +
                  ss[128 + tid] * __builtin_amdgcn_exp2f(m2 - M) +
                  ss[192 + tid] * __builtin_amdgcn_exp2f(m3 - M);
        v = EPS_LOGN - EPS_LN2 * (M + log2f(S));
    }
    return v;
}

// ---------------- sinkhorn half: two-pass (VERIFIED core), CHUNK=64 ---------
// lse single-float partial format (verified round 8). BYTE-IDENTICAL to r8.
__global__ __launch_bounds__(256) void egf_sink_half8(const float4* __restrict__ pts,
                                                      const float* __restrict__ Pin,
                                                      float* __restrict__ Pout,
                                                      int dir, int init) {
    int q = blockIdx.z; int b = q / 3, t = q - b * 3;
    int xsel = (t == 2) ? 1 : 0;
    int ysel = (t == 1) ? 0 : 1;
    const float4* rowP = pts + (b * 2 + (dir ? ysel : xsel)) * NPTS;
    const float4* colP = pts + (b * 2 + (dir ? xsel : ysel)) * NPTS;

    __shared__ float4 srow[CHUNK];
    __shared__ float sm[256], ss[256];
    int tid = threadIdx.x;
    int chunk = blockIdx.y;
    int r_local = tid & 63, h = tid >> 6;
    int row = chunk * CHUNK + r_local;

    // prefetch column fragments (independent of the staging barrier)
    int col0 = blockIdx.x * COLS_PER_BLK + tid;
    float4 cf[8];
#pragma unroll
    for (int k = 0; k < 8; k++) cf[k] = colP[col0 + k * 256];

    float v = 0.0f;
    if (!init)
        v = stageCombine(Pin, q * QSTRIDE, row, h, r_local, sm, ss, tid);
    if (tid < 64) {
        float4 pp = rowP[row];
        srow[tid] = make_float4(pp.x * INV_EPS_L2E, pp.y * INV_EPS_L2E,
                                pp.z * INV_EPS_L2E, (v - pp.w) * INV_EPS_L2E);
    }
    __syncthreads();

    v2f cx[4], cy[4], cz[4], cw[4];
#pragma unroll
    for (int p = 0; p < 4; p++) {
        cx[p] = (v2f){cf[2 * p].x, cf[2 * p + 1].x};
        cy[p] = (v2f){cf[2 * p].y, cf[2 * p + 1].y};
        cz[p] = (v2f){cf[2 * p].z, cf[2 * p + 1].z};
        cw[p] = (v2f){cf[2 * p].w * INV_EPS_L2E, cf[2 * p + 1].w * INV_EPS_L2E};
    }
    v2f mx[4];
#pragma unroll
    for (int p = 0; p < 4; p++) mx[p] = (v2f){-3.4e38f, -3.4e38f};
#pragma unroll 4
    for (int rr = 0; rr < CHUNK; rr++) {
        float4 rp = srow[rr];
        v2f rxy = (v2f){rp.x, rp.y};
        v2f rzw = (v2f){rp.z, rp.w};
#pragma unroll
        for (int p = 0; p < 4; p++) {
            v2f e = pk_fma_blo_chi(rzw, cz[p], rzw);   // Z*cz + W
            e = pk_fma_bhi(rxy, cy[p], e);             // + Y*cy
            e = pk_fma_blo(rxy, cx[p], e);             // + X*cx
            mx[p].x = fmaxf(mx[p].x, e.x);
            mx[p].y = fmaxf(mx[p].y, e.y);
        }
    }
    v2f mneg[4], sa[4];
#pragma unroll
    for (int p = 0; p < 4; p++) { mneg[p] = -mx[p]; sa[p] = (v2f){0.0f, 0.0f}; }
#pragma unroll 4
    for (int rr = 0; rr < CHUNK; rr++) {
        float4 rp = srow[rr];
        v2f rxy = (v2f){rp.x, rp.y};
        v2f rzw = (v2f){rp.z, rp.w};
#pragma unroll
        for (int p = 0; p < 4; p++) {
            v2f e = pk_fma_blo(rzw, cz[p], mneg[p]);   // Z*cz - mx
            e = pk_fma_bhi(rxy, cy[p], e);             // + Y*cy
            e = pk_fma_blo(rxy, cx[p], e);             // + X*cx
            e = pk_add_bhi(e, rzw);                    // + W
            v2f ex;
            ex.x = __builtin_amdgcn_exp2f(e.x);
            ex.y = __builtin_amdgcn_exp2f(e.y);
            sa[p] = pk_add(sa[p], ex);
        }
    }
    float* om = Pout + q * QSTRIDE + chunk * NPTS;
#pragma unroll
    for (int p = 0; p < 4; p++) {
        om[col0 + (2 * p) * 256]     = mx[p].x - cw[p].x + log2f(sa[p].x);
        om[col0 + (2 * p + 1) * 256] = mx[p].y - cw[p].y + log2f(sa[p].y);
    }
}

// ---------------- final scalar assembly (device helper) ----------------
__device__ __forceinline__ void finalize_body(float* acc, float* out) {
    auto rd = [&](int i) -> float { return atomicAdd(&acc[i], 0.0f); };
    const float AREA = 246.0f * 246.0f;
    float ssim_m = 1.0f - (rd(A_SSIMA) + rd(A_SSIMA + 1)) / (2.0f * AREA);
    float ssim_p = 1.0f - (rd(A_SSIMB) + rd(A_SSIMB + 1)) / (2.0f * 3.0f * AREA);
    float g_cons = rd(A_CH1) / (2.0f * 65536.0f) + rd(A_CH2) / (2.0f * 16384.0f);
    float aux = rd(A_AUX) / (2.0f * 65536.0f);
    float inc0 = (rd(A_CNT)     >= 31.5f) ? 1.0f : 0.0f;
    float inc1 = (rd(A_CNT + 1) >= 31.5f) ? 1.0f : 0.0f;
    float v0 = rd(A_SINK + 0), v1 = rd(A_SINK + 1), v2 = rd(A_SINK + 2);
    float v3 = rd(A_SINK + 3), v4 = rd(A_SINK + 4), v5 = rd(A_SINK + 5);
    float Lt = (inc0 * (v0 - 0.5f * v1 - 0.5f * v2) +
                inc1 * (v3 - 0.5f * v4 - 0.5f * v5)) * 0.5f;
    float Lo = (inc0 * rd(A_LOUT) + inc1 * rd(A_LOUT + 1)) / (3.0f * 65536.0f) * 0.5f;
    float Ls = (inc0 * (1.0f - rd(A_SSIMC) / (3.0f * AREA)) +
                inc1 * (1.0f - rd(A_SSIMC + 1) / (3.0f * AREA))) * 0.5f;
    float Li = 2.5f * rd(A_INT) / (2.0f * 3.0f * 65536.0f);
    float Lsm = rd(A_SMOOTH) / (2.0f * 3.0f * 65536.0f);
    float total = 0.8f * Lt + 0.3f * Lo + 0.5f * Ls + Li + 0.2f * Lsm;
    out[0] = total; out[1] = ssim_m; out[2] = ssim_p; out[3] = g_cons; out[4] = aux;
}

// ---------------- sinkhorn value + last-block finalize ----------------
// grid (128, 6): blockIdx.x>>6 selects f/g partials, &63 selects the 64-row chunk.
__global__ __launch_bounds__(256) void egf_sink_val8(const float* __restrict__ Pf,
                                                     const float* __restrict__ Pg,
                                                     float* __restrict__ acc,
                                                     float* __restrict__ out) {
    int q = blockIdx.y;
    int side = blockIdx.x >> 6;
    int chunk = blockIdx.x & 63;
    const float* P = side ? Pg : Pf;
    __shared__ float sm[256], ss[256];
    int tid = threadIdx.x;
    int r_local = tid & 63, h = tid >> 6;
    int row = chunk * CHUNK + r_local;
    float v = stageCombine(P, q * QSTRIDE, row, h, r_local, sm, ss, tid);
    float tot = blockSum(v, tid);
    if (tid == 0) {
        atomicAdd(&acc[A_SINK + q], tot * (1.0f / 4096.0f));
        __threadfence();
        unsigned old = atomicAdd((unsigned*)&acc[A_DONE], 1u);
        if (old == 128u * 6u - 1u) finalize_body(acc, out);   // last block finalizes
    }
}

// ---------------- host launch ----------------
extern "C" void kernel_launch(void* const* d_in, const int* in_sizes, int n_in,
                              void* d_out, int out_size, void* d_ws, size_t ws_size,
                              hipStream_t stream) {
    const float* y    = (const float*)d_in[0];
    const float* mri  = (const float*)d_in[1];
    const float* pet  = (const float*)d_in[2];
    const float* mask = (const float*)d_in[3];
    const float* ehat = (const float*)d_in[4];
    const int*   idx  = (const int*)d_in[5];
    float* out = (float*)d_out;
    float* ws  = (float*)d_ws;

    float* acc   = ws;                    // 64 floats
    float4* pts  = (float4*)(ws + 64);    // 4*4096 float4 = 65536 floats
    float* base  = ws + 64 + 65536;

    // sinkhorn partials: 2 float planes of 6*64*4096 elements (6.3 MB apiece)
    float* Pf = base;
    float* Pg = Pf + QSTRIDE * 6;
    float* ibase = base + 2 * QSTRIDE * 6;

    // image scratch
    float* ygray    = ibase;              // 131072
    float* py       = ygray + 131072;     // 32768
    float* pmri     = py + 32768;         // 32768
    float* mag_yg   = pmri + 32768;       // 131072
    float* mag_mri  = mag_yg + 131072;    // 131072
    float* mag_py   = mag_mri + 131072;   // 32768
    float* mag_pmri = mag_py + 32768;     // 32768

    hipMemsetAsync(acc, 0, 64 * sizeof(float), stream);

    unsigned* mx = (unsigned*)(acc + A_MAX);

    egf_prep_pool<<<dim3(84, 2), 256, 0, stream>>>(y, pet, mri, mask, idx,
                                                   ygray, py, pmri, pts, acc);
    egf_sobel4<<<dim3(160, 2), 256, 0, stream>>>(ygray, mri, py, pmri,
                                                 mag_yg, mag_mri, mag_py, mag_pmri, mx);
    egf_charb2<<<dim3(80, 2), 256, 0, stream>>>(mag_yg, mag_mri, mag_py, mag_pmri, mx, ehat, acc);
    egf_ssim3<<<dim3(8, 8, 14), dim3(16, 16), 0, stream>>>(y, ygray, mri, pet, mask, acc);
    egf_smooth1<<<dim3(8, 8, 6), 256, 0, stream>>>(y, acc + A_SMOOTH);

    dim3 sgrid(NCB, NCH, 6);   // 2 x 64 x 6 = 768 blocks
    for (int it = 0; it < 11; ++it) {
        egf_sink_half8<<<sgrid, 256, 0, stream>>>(pts, Pf, Pg, 0, it == 0 ? 1 : 0);
        egf_sink_half8<<<sgrid, 256, 0, stream>>>(pts, Pg, Pf, 1, 0);
    }
    egf_sink_val8<<<dim3(128, 6), 256, 0, stream>>>(Pf, Pg, acc, out);
}